// Round 10
// baseline (374.942 us; speedup 1.0000x reference)
//
#include <hip/hip_runtime.h>
#include <hip/hip_bf16.h>

typedef unsigned short u16;
typedef __attribute__((ext_vector_type(8))) short bf16x8;
typedef __attribute__((ext_vector_type(4))) float f32x4;

#define BTOK 4096
#define DDIM 1024
#define NEXP 8
#define HDIM 4096
#define ODIM 1024
#define MAXT 23              // max 256-row tiles: 16 + 7
#define MROWS (MAXT * 256)   // 5888

__device__ __forceinline__ u16 f2bf(float f) {
  unsigned u = __float_as_uint(f);
  return (u16)((u + 0x7FFFu + ((u >> 16) & 1u)) >> 16);  // RNE
}
__device__ __forceinline__ u16 cvt_bf(float f) {  // HW cvt, RNE
  __hip_bfloat16 h = __float2bfloat16(f);
  u16 r;
  __builtin_memcpy(&r, &h, 2);
  return r;
}

__device__ __forceinline__ void gload16(const void* g, void* l) {
  __builtin_amdgcn_global_load_lds(
      (const __attribute__((address_space(1))) void*)g,
      (__attribute__((address_space(3))) void*)l, 16, 0, 0);
}

// ---------------- init: clear control block + rowmap ----------------
__global__ __launch_bounds__(256) void init_kernel(int* __restrict__ ctrl,
                                                   int* __restrict__ rowmap) {
  int i = blockIdx.x * 256 + threadIdx.x;  // grid 27*256 = 6912
  if (i < 1024)
    ctrl[i] = 0;
  else
    rowmap[i - 1024] = -1;  // 5888 entries
}

// ---------------- gating: one wave per token, fp64 accumulate ----------------
__global__ __launch_bounds__(256) void gate_kernel(
    const float* __restrict__ x, const float* __restrict__ Wg,
    const float* __restrict__ bg, int* __restrict__ assign,
    int* __restrict__ counts) {
  int wave = threadIdx.x >> 6;
  int lane = threadIdx.x & 63;
  int b = blockIdx.x * 4 + wave;
  const float* xr = x + (size_t)b * DDIM;
  double acc[NEXP];
#pragma unroll
  for (int e = 0; e < NEXP; ++e) acc[e] = 0.0;
  for (int d = lane; d < DDIM; d += 64) {
    float xv = xr[d];
    const float4* wrow = (const float4*)(Wg + d * NEXP);
    float4 w0 = wrow[0], w1 = wrow[1];
    acc[0] += (double)xv * (double)w0.x;
    acc[1] += (double)xv * (double)w0.y;
    acc[2] += (double)xv * (double)w0.z;
    acc[3] += (double)xv * (double)w0.w;
    acc[4] += (double)xv * (double)w1.x;
    acc[5] += (double)xv * (double)w1.y;
    acc[6] += (double)xv * (double)w1.z;
    acc[7] += (double)xv * (double)w1.w;
  }
#pragma unroll
  for (int e = 0; e < NEXP; ++e) {
    double v = acc[e];
#pragma unroll
    for (int off = 32; off > 0; off >>= 1) v += __shfl_xor(v, off);
    acc[e] = v;
  }
  if (lane == 0) {
    int best = 0;
    double bv = acc[0] + (double)bg[0];
#pragma unroll
    for (int e = 1; e < NEXP; ++e) {
      double v = acc[e] + (double)bg[e];
      if (v > bv) { bv = v; best = e; }  // first max wins (matches jnp.argmax)
    }
    assign[b] = best;
    atomicAdd(&counts[best], 1);
  }
}

// ---------------- setup: offsets (256-padded), tile table, balance loss ------
__global__ void setup_kernel(const int* __restrict__ counts,
                             const float* __restrict__ wbal,
                             int* __restrict__ offp, int* __restrict__ tile_e,
                             int* __restrict__ tile_m, int* __restrict__ meta,
                             float* __restrict__ loss_out) {
  if (threadIdx.x != 0 || blockIdx.x != 0) return;
  int off = 0, nt = 0;
  for (int e = 0; e < NEXP; ++e) {
    offp[e] = off;
    int pc = (counts[e] + 255) & ~255;  // pad to 256
    for (int t = 0; t < (pc >> 8); ++t) {
      tile_e[nt] = e;
      tile_m[nt] = off + t * 256;
      ++nt;
    }
    off += pc;
  }
  offp[NEXP] = off;
  meta[0] = nt;
  float mean = (float)BTOK / (float)NEXP;
  float s = 0.f;
  for (int e = 0; e < NEXP; ++e) {
    float d = (float)counts[e] - mean;
    s += d * d;
  }
  loss_out[0] = s / (float)NEXP * wbal[0];
}

// ---------------- gather: token -> per-expert bucket, fp32 -> bf16 ------------
__global__ __launch_bounds__(256) void gather_kernel(
    const float* __restrict__ x, const int* __restrict__ assign,
    const int* __restrict__ offp, int* __restrict__ fill,
    int* __restrict__ rowmap, u16* __restrict__ xg) {
  int b = blockIdx.x;
  __shared__ int srow;
  if (threadIdx.x == 0) {
    int e = assign[b];
    int pos = atomicAdd(&fill[e], 1);
    int row = offp[e] + pos;
    rowmap[row] = b;
    srow = row;
  }
  __syncthreads();
  int row = srow;
  float4 v = *(const float4*)(x + (size_t)b * DDIM + threadIdx.x * 4);
  ushort4 o;
  o.x = f2bf(v.x);
  o.y = f2bf(v.y);
  o.z = f2bf(v.z);
  o.w = f2bf(v.w);
  *(ushort4*)(xg + (size_t)row * DDIM + threadIdx.x * 4) = o;
}

// ---------------- transpose v2: fp32 [K][N] -> bf16 [N][K] -------------------
// Block: 128k x 64n. Loads 8x float4 in flight (MLP), LDS fp32 pass, each
// thread writes one contiguous 64-B K-run (vs old 32-B scatter).
__global__ __launch_bounds__(256) void transpose_conv(
    const float* __restrict__ W, u16* __restrict__ wt, int N, int K) {
  const int e = blockIdx.z;
  const int kb = blockIdx.x * 128, nb = blockIdx.y * 64;
  __shared__ __align__(16) float lds[128][68];
  const float* src = W + (size_t)e * K * N;
  const int t = threadIdx.x;
  const int rr = t >> 4, cc = (t & 15) * 4;
#pragma unroll
  for (int p = 0; p < 8; ++p) {
    float4 v =
        *(const float4*)(src + (size_t)(kb + rr + p * 16) * N + nb + cc);
    *(float4*)&lds[rr + p * 16][cc] = v;
  }
  __syncthreads();
  const int n = t & 63, ks = (t >> 6) * 32;
  alignas(16) u16 tmp[32];
#pragma unroll
  for (int i = 0; i < 32; ++i) tmp[i] = cvt_bf(lds[ks + i][n]);
  u16* dst = wt + ((size_t)e * N + nb + n) * K + kb + ks;
  *(float4*)dst = *(float4*)&tmp[0];
  *(float4*)(dst + 8) = *(float4*)&tmp[8];
  *(float4*)(dst + 16) = *(float4*)&tmp[16];
  *(float4*)(dst + 24) = *(float4*)&tmp[24];
}

// ---------------- GEMM core: 256x128 tile, 8 waves, BK=32, 3-buf vmcnt(3) ----
// Wave tile 64x64 (4 waves M x 2 waves N). Both operands bf16 K-contig via
// global_load_lds: A 1024 16B-units (2/thread), B 512 (1/thread), into 3-buf
// rotation staged 2 ahead; vmcnt(3) before each barrier keeps the next stage's
// 3 loads in flight (T4). LDS swizzle unit(r,kq) = r*4 + (kq ^ ((r>>1)&3)):
// b128 frag reads 2-way bank-aliased (free). setprio(1) around MFMA (T5).
// MODE 0: Hout = relu(acc + bias) bf16;  MODE 1: P[z] = acc (fp32 partials)
template <int MODE>
__device__ __forceinline__ void gemm_core(
    u16* lds, int bx, int by, int bz, const u16* __restrict__ A, int lda,
    const u16* __restrict__ BT, int ldb, int nbRows,
    const float* __restrict__ bias, const int* __restrict__ tile_e,
    const int* __restrict__ tile_m, u16* __restrict__ Hout, int ldn,
    float* __restrict__ P, size_t pStride, int nkt) {
  const int e = tile_e[bx];
  const int m0 = tile_m[bx];
  const int n0 = by * 128;
  const int kOff = bz * nkt * 32;

  const int tid = threadIdx.x;  // [0,512)
  const int lane = tid & 63;
  const int wave = tid >> 6;
  const int wr = wave >> 1, wc = wave & 1;  // 4 x 2 waves
  const int fr = lane & 15;
  const int kqr = lane >> 4;

  // staging source (inverse swizzle): A units tid, tid+512; B unit tid
  const int r0 = tid >> 2, k0 = (tid & 3) ^ ((r0 >> 1) & 3);
  const int r1 = (tid + 512) >> 2, k1 = ((tid + 512) & 3) ^ ((r1 >> 1) & 3);
  const u16* aS0 = A + (size_t)(m0 + r0) * lda + kOff + k0 * 8;
  const u16* aS1 = A + (size_t)(m0 + r1) * lda + kOff + k1 * 8;
  const u16* bPan = BT + ((size_t)e * nbRows + n0) * ldb + kOff;
  const u16* bS0 = bPan + (size_t)r0 * ldb + k0 * 8;
  const int dstA0 = (tid & ~63) * 8;          // u16 units, lane-linear per wave
  const int dstA1 = dstA0 + 512 * 8;
  const int dstB = (tid & ~63) * 8;

  // fragment offsets (u16 units, swizzled); B region at +8192 u16
  int aOff[4], bOff[4];
#pragma unroll
  for (int i = 0; i < 4; ++i) {
    int r = wr * 64 + i * 16 + fr;  // [0,256)
    aOff[i] = (r * 4 + (kqr ^ ((r >> 1) & 3))) * 8;
    int c = wc * 64 + i * 16 + fr;  // [0,128)
    bOff[i] = 8192 + (c * 4 + (kqr ^ ((c >> 1) & 3))) * 8;
  }

  f32x4 acc[4][4];
#pragma unroll
  for (int i = 0; i < 4; ++i)
#pragma unroll
    for (int j = 0; j < 4; ++j)
#pragma unroll
      for (int r = 0; r < 4; ++r) acc[i][j][r] = 0.f;

  auto stage = [&](int buf, int kt) {
    const int ko = kt * 32;
    u16* base = lds + buf * 12288;  // 24 KB per buffer
    gload16(aS0 + ko, base + dstA0);
    gload16(aS1 + ko, base + dstA1);
    gload16(bS0 + ko, base + 8192 + dstB);
  };
  auto compute = [&](int buf) {
    const u16* base = lds + buf * 12288;
    bf16x8 af[4], bfr[4];
#pragma unroll
    for (int i = 0; i < 4; ++i) {
      af[i] = *(const bf16x8*)(base + aOff[i]);
      bfr[i] = *(const bf16x8*)(base + bOff[i]);
    }
    __builtin_amdgcn_s_setprio(1);
#pragma unroll
    for (int i = 0; i < 4; ++i)
#pragma unroll
      for (int j = 0; j < 4; ++j)
        acc[i][j] = __builtin_amdgcn_mfma_f32_16x16x32_bf16(af[i], bfr[j],
                                                            acc[i][j], 0, 0, 0);
    __builtin_amdgcn_s_setprio(0);
  };

  // prologue: stage t=0,1; retire t=0's 3 loads; barrier
  stage(0, 0);
  stage(1, 1);
  __builtin_amdgcn_sched_barrier(0);
  asm volatile("s_waitcnt vmcnt(3)" ::: "memory");
  __builtin_amdgcn_s_barrier();
  __builtin_amdgcn_sched_barrier(0);

  int cur = 0, nst = 2;
#pragma unroll 1
  for (int t = 0; t < nkt; ++t) {
    const bool more = (t + 2 < nkt);
    if (more) stage(nst, t + 2);
    compute(cur);
    cur = (cur == 2) ? 0 : cur + 1;
    nst = (nst == 2) ? 0 : nst + 1;
    if (t + 1 < nkt) {
      __builtin_amdgcn_sched_barrier(0);
      if (more)
        asm volatile("s_waitcnt vmcnt(3)" ::: "memory");  // t+1 done, t+2 fly
      else
        asm volatile("s_waitcnt vmcnt(0)" ::: "memory");  // tail drain
      __builtin_amdgcn_s_barrier();
      __builtin_amdgcn_sched_barrier(0);
    }
  }

  // epilogue: C/D layout col = lane&15, row = (lane>>4)*4 + reg
  if constexpr (MODE == 0) {
#pragma unroll
    for (int i = 0; i < 4; ++i) {
      int rbase = m0 + wr * 64 + i * 16 + (lane >> 4) * 4;
#pragma unroll
      for (int j = 0; j < 4; ++j) {
        int col = n0 + wc * 64 + j * 16 + fr;
        float bv = bias[e * ldn + col];
#pragma unroll
        for (int r = 0; r < 4; ++r) {
          float v = acc[i][j][r] + bv;
          v = v > 0.f ? v : 0.f;
          Hout[(size_t)(rbase + r) * ldn + col] = f2bf(v);
        }
      }
    }
  } else {
    float* Pp = P + bz * pStride;
#pragma unroll
    for (int i = 0; i < 4; ++i) {
      int rbase = m0 + wr * 64 + i * 16 + (lane >> 4) * 4;
#pragma unroll
      for (int j = 0; j < 4; ++j) {
        int col = n0 + wc * 64 + j * 16 + fr;
#pragma unroll
        for (int r = 0; r < 4; ++r)
          Pp[(size_t)(rbase + r) * ODIM + col] = acc[i][j][r];
      }
    }
  }
}

// ---------------- GEMM1: xg @ wt1 -> h (relu+bias) ----------------
// XCD map: xcd = orig&7 owns 4 N-panels; by marches fastest within bx so the
// 4 B-panels (4 x 256 KB) stay L2-resident and each A panel is reused 4x.
__global__ __launch_bounds__(512, 4) void moe_gemm1(
    const u16* __restrict__ xg, const u16* __restrict__ wt1,
    const float* __restrict__ b1, const int* __restrict__ tile_e,
    const int* __restrict__ tile_m, const int* __restrict__ meta,
    u16* __restrict__ h) {
  __shared__ __align__(16) u16 lds[3 * 12288];  // 72 KB
  const int orig = blockIdx.y * MAXT + blockIdx.x;  // nwg = 23*32 = 736
  const int xcd = orig & 7;
  const int i = orig >> 3;  // [0,92)
  const int bx = i >> 2;
  const int by = xcd * 4 + (i & 3);
  if (bx >= meta[0]) return;
  gemm_core<0>(lds, bx, by, 0, xg, DDIM, wt1, DDIM, HDIM, b1, tile_e, tile_m,
               h, HDIM, nullptr, 0, DDIM / 32);
}

// ---------------- GEMM2: h @ wt2 -> P (z-split K, z=2) ----------------
// Per z: 184 blocks = 8 XCD x 23; each XCD owns one N-panel (512 KB, L2-res).
__global__ __launch_bounds__(512, 4) void moe_gemm2(
    const u16* __restrict__ h, const u16* __restrict__ wt2,
    const int* __restrict__ tile_e, const int* __restrict__ tile_m,
    const int* __restrict__ meta, float* __restrict__ P, size_t pStride) {
  __shared__ __align__(16) u16 lds[3 * 12288];
  const int orig = blockIdx.y * MAXT + blockIdx.x;  // nwg per z = 184
  const int xcd = orig & 7;
  const int i = orig >> 3;  // [0,23)
  const int bx = i;
  const int by = xcd;
  if (bx >= meta[0]) return;
  gemm_core<1>(lds, bx, by, blockIdx.z, h, HDIM, wt2, HDIM, ODIM, nullptr,
               tile_e, tile_m, nullptr, 0, P, pStride, (HDIM / 2) / 32);
}

// ---------------- reduce: out[tok] = P0 + P1 + b2 ----------------
__global__ __launch_bounds__(256) void reduce_kernel(
    const float* __restrict__ P, size_t pStride, const int* __restrict__ rowmap,
    const int* __restrict__ tile_e, const int* __restrict__ tile_m,
    const int* __restrict__ meta, const float* __restrict__ b2,
    float* __restrict__ out) {
  if ((int)blockIdx.x >= meta[0]) return;
  const int e = tile_e[blockIdx.x];
  const int m0 = tile_m[blockIdx.x];
  const int c0 = blockIdx.y * 128;
#pragma unroll 1
  for (int it = 0; it < 32; ++it) {
    int idx = it * 256 + threadIdx.x;  // 8192 float4 per block (256 rows)
    int r = idx >> 5, cq = idx & 31;
    int row = m0 + r;
    int tok = rowmap[row];
    if (tok < 0) continue;
    int c = c0 + cq * 4;
    float4 a = *(const float4*)(P + (size_t)row * ODIM + c);
    float4 b = *(const float4*)(P + pStride + (size_t)row * ODIM + c);
    float4 bb = *(const float4*)(b2 + (size_t)e * ODIM + c);
    float4 o;
    o.x = a.x + b.x + bb.x;
    o.y = a.y + b.y + bb.y;
    o.z = a.z + b.z + bb.z;
    o.w = a.w + b.w + bb.w;
    *(float4*)(out + (size_t)tok * ODIM + c) = o;
  }
}

extern "C" void kernel_launch(void* const* d_in, const int* in_sizes, int n_in,
                              void* d_out, int out_size, void* d_ws,
                              size_t ws_size, hipStream_t stream) {
  const float* x = (const float*)d_in[0];
  const float* Wg = (const float*)d_in[1];
  const float* bg = (const float*)d_in[2];
  const float* W1 = (const float*)d_in[3];
  const float* b1 = (const float*)d_in[4];
  const float* W2 = (const float*)d_in[5];
  const float* b2 = (const float*)d_in[6];
  const float* wbal = (const float*)d_in[7];
  float* out = (float*)d_out;

  char* ws = (char*)d_ws;
  int* counts = (int*)(ws + 0);
  int* fill = (int*)(ws + 64);
  int* offp = (int*)(ws + 128);
  int* meta = (int*)(ws + 192);
  int* tile_e = (int*)(ws + 256);
  int* tile_m = (int*)(ws + 512);
  int* assign = (int*)(ws + 4096);
  int* rowmap = (int*)(ws + 20480);        // 5888 ints
  u16* xg = (u16*)(ws + 65536);            // 5888x1024 bf16     (12.1 MB)
  u16* h = (u16*)(ws + 12582912);          // 5888x4096 bf16     (48.2 MB)
  float* P = (float*)(ws + 61865984);      // 2x5888x1024 fp32   (48.2 MB)
  u16* wt1 = (u16*)(ws + 110100480);       // [8][4096][1024] bf16 (67.1 MB)
  u16* wt2 = (u16*)(ws + 177209344);       // [8][1024][4096] bf16 (67.1 MB)
  const size_t pStride = (size_t)MROWS * ODIM;

  init_kernel<<<27, 256, 0, stream>>>((int*)ws, rowmap);
  gate_kernel<<<BTOK / 4, 256, 0, stream>>>(x, Wg, bg, assign, counts);
  setup_kernel<<<1, 64, 0, stream>>>(counts, wbal, offp, tile_e, tile_m, meta,
                                     out + (size_t)BTOK * ODIM);
  gather_kernel<<<BTOK, 256, 0, stream>>>(x, assign, offp, fill, rowmap, xg);

  // W1 [1024][4096] -> wt1 [8][4096][1024]
  transpose_conv<<<dim3(DDIM / 128, HDIM / 64, NEXP), 256, 0, stream>>>(
      W1, wt1, HDIM, DDIM);
  // W2 [4096][1024] -> wt2 [8][1024][4096]
  transpose_conv<<<dim3(HDIM / 128, ODIM / 64, NEXP), 256, 0, stream>>>(
      W2, wt2, ODIM, HDIM);

  moe_gemm1<<<dim3(MAXT, HDIM / 128), 512, 0, stream>>>(
      xg, wt1, b1, tile_e, tile_m, meta, h);
  moe_gemm2<<<dim3(MAXT, ODIM / 128, 2), 512, 0, stream>>>(
      h, wt2, tile_e, tile_m, meta, P, pStride);
  reduce_kernel<<<dim3(MAXT, ODIM / 128), 256, 0, stream>>>(
      P, pStride, rowmap, tile_e, tile_m, meta, b2, out);
}

// Round 11
// 363.081 us; speedup vs baseline: 1.0327x; 1.0327x over previous
//
#include <hip/hip_runtime.h>
#include <hip/hip_bf16.h>

typedef unsigned short u16;
typedef __attribute__((ext_vector_type(8))) short bf16x8;
typedef __attribute__((ext_vector_type(4))) float f32x4;

#define BTOK 4096
#define DDIM 1024
#define NEXP 8
#define HDIM 4096
#define ODIM 1024
#define MAXTILES 40
#define MAXROWS (MAXTILES * 128)  // 5120

__device__ __forceinline__ u16 f2bf(float f) {
  unsigned u = __float_as_uint(f);
  return (u16)((u + 0x7FFFu + ((u >> 16) & 1u)) >> 16);  // RNE
}
__device__ __forceinline__ u16 cvt_bf(float f) {  // HW cvt, RNE
  __hip_bfloat16 h = __float2bfloat16(f);
  u16 r;
  __builtin_memcpy(&r, &h, 2);
  return r;
}

__device__ __forceinline__ void gload16(const void* g, void* l) {
  __builtin_amdgcn_global_load_lds(
      (const __attribute__((address_space(1))) void*)g,
      (__attribute__((address_space(3))) void*)l, 16, 0, 0);
}

// ---------------- init: clear control block + rowmap ----------------
__global__ __launch_bounds__(256) void init_kernel(int* __restrict__ ctrl,
                                                   int* __restrict__ rowmap) {
  int i = blockIdx.x * 256 + threadIdx.x;  // grid 24*256 = 6144
  if (i < 1024)
    ctrl[i] = 0;
  else
    rowmap[i - 1024] = -1;  // 5120 entries
}

// ---------------- gating: one wave per token, fp64 accumulate ----------------
__global__ __launch_bounds__(256) void gate_kernel(
    const float* __restrict__ x, const float* __restrict__ Wg,
    const float* __restrict__ bg, int* __restrict__ assign,
    int* __restrict__ counts) {
  int wave = threadIdx.x >> 6;
  int lane = threadIdx.x & 63;
  int b = blockIdx.x * 4 + wave;
  const float* xr = x + (size_t)b * DDIM;
  double acc[NEXP];
#pragma unroll
  for (int e = 0; e < NEXP; ++e) acc[e] = 0.0;
  for (int d = lane; d < DDIM; d += 64) {
    float xv = xr[d];
    const float4* wrow = (const float4*)(Wg + d * NEXP);
    float4 w0 = wrow[0], w1 = wrow[1];
    acc[0] += (double)xv * (double)w0.x;
    acc[1] += (double)xv * (double)w0.y;
    acc[2] += (double)xv * (double)w0.z;
    acc[3] += (double)xv * (double)w0.w;
    acc[4] += (double)xv * (double)w1.x;
    acc[5] += (double)xv * (double)w1.y;
    acc[6] += (double)xv * (double)w1.z;
    acc[7] += (double)xv * (double)w1.w;
  }
#pragma unroll
  for (int e = 0; e < NEXP; ++e) {
    double v = acc[e];
#pragma unroll
    for (int off = 32; off > 0; off >>= 1) v += __shfl_xor(v, off);
    acc[e] = v;
  }
  if (lane == 0) {
    int best = 0;
    double bv = acc[0] + (double)bg[0];
#pragma unroll
    for (int e = 1; e < NEXP; ++e) {
      double v = acc[e] + (double)bg[e];
      if (v > bv) { bv = v; best = e; }  // first max wins (matches jnp.argmax)
    }
    assign[b] = best;
    atomicAdd(&counts[best], 1);
  }
}

// ---------------- setup: offsets (128-padded), tile table, balance loss ------
__global__ void setup_kernel(const int* __restrict__ counts,
                             const float* __restrict__ wbal,
                             int* __restrict__ offp, int* __restrict__ tile_e,
                             int* __restrict__ tile_m, int* __restrict__ meta,
                             float* __restrict__ loss_out) {
  if (threadIdx.x != 0 || blockIdx.x != 0) return;
  int off = 0, nt = 0;
  for (int e = 0; e < NEXP; ++e) {
    offp[e] = off;
    int pc = (counts[e] + 127) & ~127;  // pad to 128
    for (int t = 0; t < (pc >> 7); ++t) {
      tile_e[nt] = e;
      tile_m[nt] = off + t * 128;
      ++nt;
    }
    off += pc;
  }
  offp[NEXP] = off;
  meta[0] = nt;
  float mean = (float)BTOK / (float)NEXP;
  float s = 0.f;
  for (int e = 0; e < NEXP; ++e) {
    float d = (float)counts[e] - mean;
    s += d * d;
  }
  loss_out[0] = s / (float)NEXP * wbal[0];
}

// ---------------- gather: token -> per-expert bucket, fp32 -> bf16 ------------
__global__ __launch_bounds__(256) void gather_kernel(
    const float* __restrict__ x, const int* __restrict__ assign,
    const int* __restrict__ offp, int* __restrict__ fill,
    int* __restrict__ rowmap, u16* __restrict__ xg) {
  int b = blockIdx.x;
  __shared__ int srow;
  if (threadIdx.x == 0) {
    int e = assign[b];
    int pos = atomicAdd(&fill[e], 1);
    int row = offp[e] + pos;
    rowmap[row] = b;
    srow = row;
  }
  __syncthreads();
  int row = srow;
  float4 v = *(const float4*)(x + (size_t)b * DDIM + threadIdx.x * 4);
  ushort4 o;
  o.x = f2bf(v.x);
  o.y = f2bf(v.y);
  o.z = f2bf(v.z);
  o.w = f2bf(v.w);
  *(ushort4*)(xg + (size_t)row * DDIM + threadIdx.x * 4) = o;
}

// ---------------- transpose v3: fp32 [K][N] -> bf16 [N][K] -------------------
// Block: 256k x 64n. 16 coalesced float4 loads/thread; LDS fp32 pass; each
// thread writes ONE CONTIGUOUS 128-B K-run (8x float4) -> full L2 sectors.
__global__ __launch_bounds__(256) void transpose_conv(
    const float* __restrict__ W, u16* __restrict__ wt, int N, int K) {
  const int e = blockIdx.z;
  const int kb = blockIdx.x * 256, nb = blockIdx.y * 64;
  __shared__ __align__(16) float lds[256][66];
  const float* src = W + (size_t)e * K * N;
  const int t = threadIdx.x;
  const int rr = t >> 4, cc = (t & 15) * 4;
#pragma unroll
  for (int p = 0; p < 16; ++p) {
    float4 v =
        *(const float4*)(src + (size_t)(kb + rr + p * 16) * N + nb + cc);
    *(float4*)&lds[rr + p * 16][cc] = v;
  }
  __syncthreads();
  const int n = t & 63, kg = (t >> 6) * 64;
  alignas(16) u16 tmp[64];
#pragma unroll
  for (int i = 0; i < 64; ++i) tmp[i] = cvt_bf(lds[kg + i][n]);
  u16* dst = wt + ((size_t)e * N + nb + n) * K + kb + kg;
#pragma unroll
  for (int q = 0; q < 8; ++q) *(float4*)(dst + q * 8) = *(float4*)&tmp[q * 8];
}

// ---------------- GEMM core: 128x128 tile, BK=32, 2-buf (round-4 proven) -----
// Both operands bf16 K-contig via global_load_lds (4/step), double-buffered
// swizzled LDS: unit(r,kq) = r*4 + (kq ^ ((r>>1)&3)) -> b128 reads 2-way
// bank-aliased (free). One __syncthreads per K-step; stage(t+1) overlaps
// compute(t); compiler drains vmcnt before the barrier.
// MODE 0: Hout = relu(acc + bias) bf16
// MODE 1: out[tok] = acc + bias  (fp32 scatter via rowmap, full K)
template <int MODE>
__device__ __forceinline__ void gemm_core(
    u16* lds, int bx, int by, const u16* __restrict__ A, int lda,
    const u16* __restrict__ BT, int ldb, int nbRows,
    const float* __restrict__ bias, const int* __restrict__ tile_e,
    const int* __restrict__ tile_m, const int* __restrict__ rowmap,
    u16* __restrict__ Hout, int ldn, float* __restrict__ Cout, int nkt) {
  const int e = tile_e[bx];
  const int m0 = tile_m[bx];
  const int n0 = by * 128;

  const int tid = threadIdx.x;
  const int lane = tid & 63;
  const int wave = tid >> 6;
  const int wr = wave >> 1, wc = wave & 1;
  const int fr = lane & 15;
  const int kqr = lane >> 4;

  // staging source (inverse swizzle), units tid and tid+256
  const int r0 = tid >> 2, k0 = (tid & 3) ^ ((r0 >> 1) & 3);
  const int r1 = (tid + 256) >> 2, k1 = ((tid + 256) & 3) ^ ((r1 >> 1) & 3);
  const u16* aS0 = A + (size_t)(m0 + r0) * lda + k0 * 8;
  const u16* aS1 = A + (size_t)(m0 + r1) * lda + k1 * 8;
  const u16* bPan = BT + ((size_t)e * nbRows + n0) * ldb;
  const u16* bS0 = bPan + (size_t)r0 * ldb + k0 * 8;
  const u16* bS1 = bPan + (size_t)r1 * ldb + k1 * 8;
  const int dst0 = (tid & ~63) * 8;  // u16 units, lane-linear per wave
  const int dst1 = dst0 + 2048;

  // fragment offsets (u16 units, swizzled)
  int aOff[4], bOff[4];
#pragma unroll
  for (int i = 0; i < 4; ++i) {
    int r = wr * 64 + i * 16 + fr;
    aOff[i] = (r * 4 + (kqr ^ ((r >> 1) & 3))) * 8;
    int c = wc * 64 + i * 16 + fr;
    bOff[i] = (c * 4 + (kqr ^ ((c >> 1) & 3))) * 8;
  }

  f32x4 acc[4][4];
#pragma unroll
  for (int i = 0; i < 4; ++i)
#pragma unroll
    for (int j = 0; j < 4; ++j)
#pragma unroll
      for (int r = 0; r < 4; ++r) acc[i][j][r] = 0.f;

  auto stage = [&](int c, int kt) {
    const int ko = kt * 32;
    u16* base = lds + c * 8192;
    gload16(aS0 + ko, base + dst0);
    gload16(aS1 + ko, base + dst1);
    gload16(bS0 + ko, base + 4096 + dst0);
    gload16(bS1 + ko, base + 4096 + dst1);
  };
  auto compute = [&](int c) {
    const u16* base = lds + c * 8192;
    bf16x8 af[4], bfr[4];
#pragma unroll
    for (int i = 0; i < 4; ++i) {
      af[i] = *(const bf16x8*)(base + aOff[i]);
      bfr[i] = *(const bf16x8*)(base + 4096 + bOff[i]);
    }
#pragma unroll
    for (int i = 0; i < 4; ++i)
#pragma unroll
      for (int j = 0; j < 4; ++j)
        acc[i][j] = __builtin_amdgcn_mfma_f32_16x16x32_bf16(af[i], bfr[j],
                                                            acc[i][j], 0, 0, 0);
  };

  // 2-phase pipeline: one barrier per K-step, stage(t+1) overlaps compute(t)
  stage(0, 0);
  __syncthreads();
  int cur = 0;
#pragma unroll 1
  for (int kt = 0; kt < nkt - 1; ++kt) {
    stage(cur ^ 1, kt + 1);
    compute(cur);
    __syncthreads();
    cur ^= 1;
  }
  compute(cur);

  // epilogue: C/D layout col = lane&15, row = (lane>>4)*4 + reg
  if constexpr (MODE == 0) {
#pragma unroll
    for (int i = 0; i < 4; ++i) {
      int rbase = m0 + wr * 64 + i * 16 + (lane >> 4) * 4;
#pragma unroll
      for (int j = 0; j < 4; ++j) {
        int col = n0 + wc * 64 + j * 16 + fr;
        float bv = bias[e * ldn + col];
#pragma unroll
        for (int r = 0; r < 4; ++r) {
          float v = acc[i][j][r] + bv;
          v = v > 0.f ? v : 0.f;
          Hout[(size_t)(rbase + r) * ldn + col] = f2bf(v);
        }
      }
    }
  } else {
#pragma unroll
    for (int i = 0; i < 4; ++i) {
      int rbase = m0 + wr * 64 + i * 16 + (lane >> 4) * 4;
      int tok[4];
#pragma unroll
      for (int r = 0; r < 4; ++r) tok[r] = rowmap[rbase + r];
#pragma unroll
      for (int j = 0; j < 4; ++j) {
        int col = n0 + wc * 64 + j * 16 + fr;
        float bv = bias[e * ldn + col];
#pragma unroll
        for (int r = 0; r < 4; ++r) {
          if (tok[r] >= 0)
            Cout[(size_t)tok[r] * ODIM + col] = acc[i][j][r] + bv;
        }
      }
    }
  }
}

// ---------------- GEMM1: xg @ wt1 -> h (relu+bias) ----------------
__global__ __launch_bounds__(256) void moe_gemm1(
    const u16* __restrict__ xg, const u16* __restrict__ wt1,
    const float* __restrict__ b1, const int* __restrict__ tile_e,
    const int* __restrict__ tile_m, const int* __restrict__ meta,
    u16* __restrict__ h) {
  __shared__ __align__(16) u16 lds[2 * 8192];  // 32 KB
  const int orig = blockIdx.y * MAXTILES + blockIdx.x;  // nwg = 1280, q = 160
  const int wg = (orig & 7) * 160 + (orig >> 3);
  const int bx = wg % MAXTILES, by = wg / MAXTILES;
  if (bx >= meta[0]) return;
  gemm_core<0>(lds, bx, by, xg, DDIM, wt1, DDIM, HDIM, b1, tile_e, tile_m,
               nullptr, h, HDIM, nullptr, DDIM / 32);
}

// ---------------- GEMM2: h @ wt2 -> out (full K, direct scatter + b2) --------
// XCD map: nwg = 320, q = 40 -> each XCD owns one by (N-panel, 1 MB L2-res)
// and marches all bx tiles.
__global__ __launch_bounds__(256) void moe_gemm2(
    const u16* __restrict__ h, const u16* __restrict__ wt2,
    const float* __restrict__ b2, const int* __restrict__ tile_e,
    const int* __restrict__ tile_m, const int* __restrict__ meta,
    const int* __restrict__ rowmap, float* __restrict__ out) {
  __shared__ __align__(16) u16 lds[2 * 8192];
  const int orig = blockIdx.y * MAXTILES + blockIdx.x;  // nwg = 320
  const int wg = (orig & 7) * 40 + (orig >> 3);
  const int bx = wg % MAXTILES, by = wg / MAXTILES;
  if (bx >= meta[0]) return;
  gemm_core<1>(lds, bx, by, h, HDIM, wt2, HDIM, ODIM, b2, tile_e, tile_m,
               rowmap, nullptr, ODIM, out, HDIM / 32);
}

extern "C" void kernel_launch(void* const* d_in, const int* in_sizes, int n_in,
                              void* d_out, int out_size, void* d_ws,
                              size_t ws_size, hipStream_t stream) {
  const float* x = (const float*)d_in[0];
  const float* Wg = (const float*)d_in[1];
  const float* bg = (const float*)d_in[2];
  const float* W1 = (const float*)d_in[3];
  const float* b1 = (const float*)d_in[4];
  const float* W2 = (const float*)d_in[5];
  const float* b2 = (const float*)d_in[6];
  const float* wbal = (const float*)d_in[7];
  float* out = (float*)d_out;

  char* ws = (char*)d_ws;
  int* counts = (int*)(ws + 0);
  int* fill = (int*)(ws + 64);
  int* offp = (int*)(ws + 128);
  int* meta = (int*)(ws + 192);
  int* tile_e = (int*)(ws + 256);
  int* tile_m = (int*)(ws + 512);
  int* assign = (int*)(ws + 4096);
  int* rowmap = (int*)(ws + 20480);        // 5120 ints
  u16* xg = (u16*)(ws + 65536);            // 5120x1024 bf16      (10.5 MB)
  u16* h = (u16*)(ws + 10551296);          // 5120x4096 bf16      (41.9 MB)
  u16* wt1 = (u16*)(ws + 52494336);        // [8][4096][1024] bf16 (67.1 MB)
  u16* wt2 = (u16*)(ws + 119603200);       // [8][1024][4096] bf16 (67.1 MB)

  init_kernel<<<24, 256, 0, stream>>>((int*)ws, rowmap);
  gate_kernel<<<BTOK / 4, 256, 0, stream>>>(x, Wg, bg, assign, counts);
  setup_kernel<<<1, 64, 0, stream>>>(counts, wbal, offp, tile_e, tile_m, meta,
                                     out + (size_t)BTOK * ODIM);
  gather_kernel<<<BTOK, 256, 0, stream>>>(x, assign, offp, fill, rowmap, xg);

  // W1 [1024][4096] -> wt1 [8][4096][1024]
  transpose_conv<<<dim3(DDIM / 256, HDIM / 64, NEXP), 256, 0, stream>>>(
      W1, wt1, HDIM, DDIM);
  // W2 [4096][1024] -> wt2 [8][1024][4096]
  transpose_conv<<<dim3(HDIM / 256, ODIM / 64, NEXP), 256, 0, stream>>>(
      W2, wt2, ODIM, HDIM);

  moe_gemm1<<<dim3(MAXTILES, HDIM / 128), 256, 0, stream>>>(
      xg, wt1, b1, tile_e, tile_m, meta, h);
  moe_gemm2<<<dim3(MAXTILES, ODIM / 128), 256, 0, stream>>>(
      h, wt2, b2, tile_e, tile_m, meta, rowmap, out);
}

// Round 12
// 352.690 us; speedup vs baseline: 1.0631x; 1.0295x over previous
//
#include <hip/hip_runtime.h>
#include <hip/hip_bf16.h>

typedef unsigned short u16;
typedef __attribute__((ext_vector_type(8))) short bf16x8;
typedef __attribute__((ext_vector_type(4))) float f32x4;

#define BTOK 4096
#define DDIM 1024
#define NEXP 8
#define HDIM 4096
#define ODIM 1024
#define MAXT 23             // max 256-row tiles: 16 + 7
#define MROWS (MAXT * 256)  // 5888

__device__ __forceinline__ u16 f2bf(float f) {
  unsigned u = __float_as_uint(f);
  return (u16)((u + 0x7FFFu + ((u >> 16) & 1u)) >> 16);  // RNE
}
__device__ __forceinline__ u16 cvt_bf(float f) {
  __hip_bfloat16 h = __float2bfloat16(f);
  u16 r;
  __builtin_memcpy(&r, &h, 2);
  return r;
}
__device__ __forceinline__ void gload16(const void* g, void* l) {
  __builtin_amdgcn_global_load_lds(
      (const __attribute__((address_space(1))) void*)g,
      (__attribute__((address_space(3))) void*)l, 16, 0, 0);
}

#define SFENCE __builtin_amdgcn_sched_barrier(0)
#define SBAR                        \
  do {                              \
    SFENCE;                         \
    __builtin_amdgcn_s_barrier();   \
    SFENCE;                         \
  } while (0)

// ---------------- init ----------------
__global__ __launch_bounds__(256) void init_kernel(int* __restrict__ ctrl,
                                                   int* __restrict__ rowmap) {
  int i = blockIdx.x * 256 + threadIdx.x;  // grid 27*256 = 6912
  if (i < 1024)
    ctrl[i] = 0;
  else
    rowmap[i - 1024] = -1;  // 5888 entries
}

// ---------------- gating ----------------
__global__ __launch_bounds__(256) void gate_kernel(
    const float* __restrict__ x, const float* __restrict__ Wg,
    const float* __restrict__ bg, int* __restrict__ assign,
    int* __restrict__ counts) {
  int wave = threadIdx.x >> 6;
  int lane = threadIdx.x & 63;
  int b = blockIdx.x * 4 + wave;
  const float* xr = x + (size_t)b * DDIM;
  double acc[NEXP];
#pragma unroll
  for (int e = 0; e < NEXP; ++e) acc[e] = 0.0;
  for (int d = lane; d < DDIM; d += 64) {
    float xv = xr[d];
    const float4* wrow = (const float4*)(Wg + d * NEXP);
    float4 w0 = wrow[0], w1 = wrow[1];
    acc[0] += (double)xv * (double)w0.x;
    acc[1] += (double)xv * (double)w0.y;
    acc[2] += (double)xv * (double)w0.z;
    acc[3] += (double)xv * (double)w0.w;
    acc[4] += (double)xv * (double)w1.x;
    acc[5] += (double)xv * (double)w1.y;
    acc[6] += (double)xv * (double)w1.z;
    acc[7] += (double)xv * (double)w1.w;
  }
#pragma unroll
  for (int e = 0; e < NEXP; ++e) {
    double v = acc[e];
#pragma unroll
    for (int off = 32; off > 0; off >>= 1) v += __shfl_xor(v, off);
    acc[e] = v;
  }
  if (lane == 0) {
    int best = 0;
    double bv = acc[0] + (double)bg[0];
#pragma unroll
    for (int e = 1; e < NEXP; ++e) {
      double v = acc[e] + (double)bg[e];
      if (v > bv) { bv = v; best = e; }
    }
    assign[b] = best;
    atomicAdd(&counts[best], 1);
  }
}

// ---------------- setup (256-pad) ----------------
__global__ void setup_kernel(const int* __restrict__ counts,
                             const float* __restrict__ wbal,
                             int* __restrict__ offp, int* __restrict__ tile_e,
                             int* __restrict__ tile_m, int* __restrict__ meta,
                             float* __restrict__ loss_out) {
  if (threadIdx.x != 0 || blockIdx.x != 0) return;
  int off = 0, nt = 0;
  for (int e = 0; e < NEXP; ++e) {
    offp[e] = off;
    int pc = (counts[e] + 255) & ~255;
    for (int t = 0; t < (pc >> 8); ++t) {
      tile_e[nt] = e;
      tile_m[nt] = off + t * 256;
      ++nt;
    }
    off += pc;
  }
  offp[NEXP] = off;
  meta[0] = nt;
  float mean = (float)BTOK / (float)NEXP;
  float s = 0.f;
  for (int e = 0; e < NEXP; ++e) {
    float d = (float)counts[e] - mean;
    s += d * d;
  }
  loss_out[0] = s / (float)NEXP * wbal[0];
}

// ---------------- gather ----------------
__global__ __launch_bounds__(256) void gather_kernel(
    const float* __restrict__ x, const int* __restrict__ assign,
    const int* __restrict__ offp, int* __restrict__ fill,
    int* __restrict__ rowmap, u16* __restrict__ xg) {
  int b = blockIdx.x;
  __shared__ int srow;
  if (threadIdx.x == 0) {
    int e = assign[b];
    int pos = atomicAdd(&fill[e], 1);
    int row = offp[e] + pos;
    rowmap[row] = b;
    srow = row;
  }
  __syncthreads();
  int row = srow;
  float4 v = *(const float4*)(x + (size_t)b * DDIM + threadIdx.x * 4);
  ushort4 o;
  o.x = f2bf(v.x);
  o.y = f2bf(v.y);
  o.z = f2bf(v.z);
  o.w = f2bf(v.w);
  *(ushort4*)(xg + (size_t)row * DDIM + threadIdx.x * 4) = o;
}

// ---------------- transpose v3 (round-11): fp32 [K][N] -> bf16 [N][K] --------
__global__ __launch_bounds__(256) void transpose_conv(
    const float* __restrict__ W, u16* __restrict__ wt, int N, int K) {
  const int e = blockIdx.z;
  const int kb = blockIdx.x * 256, nb = blockIdx.y * 64;
  __shared__ __align__(16) float lds[256][66];
  const float* src = W + (size_t)e * K * N;
  const int t = threadIdx.x;
  const int rr = t >> 4, cc = (t & 15) * 4;
#pragma unroll
  for (int p = 0; p < 16; ++p) {
    float4 v =
        *(const float4*)(src + (size_t)(kb + rr + p * 16) * N + nb + cc);
    *(float4*)&lds[rr + p * 16][cc] = v;
  }
  __syncthreads();
  const int n = t & 63, kg = (t >> 6) * 64;
  alignas(16) u16 tmp[64];
#pragma unroll
  for (int i = 0; i < 64; ++i) tmp[i] = cvt_bf(lds[kg + i][n]);
  u16* dst = wt + ((size_t)e * N + nb + n) * K + kb + kg;
#pragma unroll
  for (int q = 0; q < 8; ++q) *(float4*)(dst + q * 8) = *(float4*)&tmp[q * 8];
}

// ---------------- 8-phase 256x256 GEMM core (m201 template port) -------------
// BM=BN=256, BK=64, 8 waves (2M x 4N), wave out = 4 scattered 64x32 patches:
// rows mq*128+wr*64+mi*16, cols nq*128+wc*32+ni*16. 16 MFMA/phase (quadrant).
// LDS 128KB: buf d(64KB) = {A-lo,A-hi,B-lo,B-hi} 16KB regions, rows 128B,
// granule swizzle g = koct ^ (r&7) (b128 frag reads at the 8-cy bank floor;
// gload_lds linear dest + inverse-permuted source keeps 128B coalescing).
// Stage 1 half-tile/phase (2 gloads/thread), 3 half-tiles in flight; counted
// vmcnt ledger: end-ph1/5 vmcnt(6), end-ph4/8 vmcnt(8) (hand-verified, incl.
// prologue + overwrite safety). setprio(1) around MFMA clusters (T5).
template <int MODE>
__device__ __forceinline__ void gemm8p_core(
    char* lds, int bx, int by, int bz, const u16* __restrict__ A, int lda,
    const u16* __restrict__ BT, int ldb, int nbRows,
    const float* __restrict__ bias, const int* __restrict__ tile_e,
    const int* __restrict__ tile_m, u16* __restrict__ Hout, int ldn,
    float* __restrict__ P, size_t pStride, int NT, int kOff) {
  const int e = tile_e[bx];
  const int m0 = tile_m[bx];
  const int n0 = by * 256;

  const int tid = threadIdx.x;  // [0,512)
  const int lane = tid & 63;
  const int wid = tid >> 6;
  const int wr = wid >> 2;  // 0..1
  const int wc = wid & 3;   // 0..3
  const int fr = lane & 15;
  const int kqr = lane >> 4;

  // staging: unit u (r=u>>3, g=u&7) holds source koct = g ^ (r&7)
  const int rS = tid >> 3, gS = tid & 7;
  const int koctOff = (gS ^ (rS & 7)) * 8;  // u16 elems
  const u16* aB0 = A + (size_t)(m0 + rS) * lda + kOff + koctOff;
  const u16* bB0 = BT + ((size_t)e * nbRows + n0 + rS) * ldb + kOff + koctOff;

  auto stageA = [&](int kt, int half) {
    char* dst = lds + (kt & 1) * 65536 + half * 16384 + tid * 16;
    const u16* s = aB0 + (size_t)(half * 128) * lda + kt * 64;
    gload16(s, dst);
    gload16(s + (size_t)64 * lda, dst + 8192);
  };
  auto stageB = [&](int kt, int half) {
    char* dst = lds + (kt & 1) * 65536 + 32768 + half * 16384 + tid * 16;
    const u16* s = bB0 + (size_t)(half * 128) * ldb + kt * 64;
    gload16(s, dst);
    gload16(s + (size_t)64 * ldb, dst + 8192);
  };

  // fragment byte offsets within a 16KB region
  int aOff[4][2], bOff[2][2];
#pragma unroll
  for (int mi = 0; mi < 4; ++mi) {
    int r = wr * 64 + mi * 16 + fr;  // [0,128)
#pragma unroll
    for (int ks = 0; ks < 2; ++ks)
      aOff[mi][ks] = r * 128 + (((ks * 4 + kqr) ^ (r & 7)) * 16);
  }
#pragma unroll
  for (int ni = 0; ni < 2; ++ni) {
    int c = wc * 32 + ni * 16 + fr;  // [0,128)
#pragma unroll
    for (int ks = 0; ks < 2; ++ks)
      bOff[ni][ks] = c * 128 + (((ks * 4 + kqr) ^ (c & 7)) * 16);
  }

  f32x4 acc[8][4];
#pragma unroll
  for (int i = 0; i < 8; ++i)
#pragma unroll
    for (int j = 0; j < 4; ++j)
#pragma unroll
      for (int r = 0; r < 4; ++r) acc[i][j][r] = 0.f;

  bf16x8 af[4][2], bA[2][2], bB[2][2];

  auto ldA = [&](int dB, int mq) {
    const char* rg = lds + dB + mq * 16384;
#pragma unroll
    for (int mi = 0; mi < 4; ++mi)
#pragma unroll
      for (int ks = 0; ks < 2; ++ks)
        af[mi][ks] = *(const bf16x8*)(rg + aOff[mi][ks]);
  };
  auto ldB = [&](int dB, int nq, bf16x8 (&bf)[2][2]) {
    const char* rg = lds + dB + 32768 + nq * 16384;
#pragma unroll
    for (int ni = 0; ni < 2; ++ni)
#pragma unroll
      for (int ks = 0; ks < 2; ++ks)
        bf[ni][ks] = *(const bf16x8*)(rg + bOff[ni][ks]);
  };
  auto MM = [&](int mq, int nq, bf16x8 (&bf)[2][2]) {
    __builtin_amdgcn_s_setprio(1);
#pragma unroll
    for (int ks = 0; ks < 2; ++ks)
#pragma unroll
      for (int mi = 0; mi < 4; ++mi)
#pragma unroll
        for (int ni = 0; ni < 2; ++ni)
          acc[mq * 4 + mi][nq * 2 + ni] = __builtin_amdgcn_mfma_f32_16x16x32_bf16(
              af[mi][ks], bf[ni][ks], acc[mq * 4 + mi][nq * 2 + ni], 0, 0, 0);
    __builtin_amdgcn_s_setprio(0);
  };

  // prologue: A-lo(0),B-lo(0) | A-hi(0),B-hi(0),A-lo(1),B-lo(1)
  stageA(0, 0);
  stageB(0, 0);
  stageA(0, 1);
  stageB(0, 1);
  stageA(1, 0);
  stageB(1, 0);
  asm volatile("s_waitcnt vmcnt(8)" ::: "memory");
  SBAR;

  const int NI = NT >> 1;
#pragma unroll 1
  for (int i = 0; i < NI; ++i) {
    const int kt1 = 2 * i + 1, kt2 = 2 * i + 2, kt3 = 2 * i + 3;
    const bool more = (i + 1 < NI);
    // ph1: kt0 (mq0,nq0)
    ldA(0, 0);
    ldB(0, 0, bA);
    stageA(kt1, 1);
    SBAR;
    asm volatile("s_waitcnt lgkmcnt(0)" ::: "memory");
    SFENCE;
    MM(0, 0, bA);
    asm volatile("s_waitcnt vmcnt(6)" ::: "memory");
    SBAR;
    // ph2: (mq0,nq1)
    ldB(0, 1, bB);
    stageB(kt1, 1);
    SBAR;
    asm volatile("s_waitcnt lgkmcnt(0)" ::: "memory");
    SFENCE;
    MM(0, 1, bB);
    SBAR;
    // ph3: (mq1,nq0)
    ldA(0, 1);
    if (more) stageA(kt2, 0);
    SBAR;
    asm volatile("s_waitcnt lgkmcnt(0)" ::: "memory");
    SFENCE;
    MM(1, 0, bA);
    SBAR;
    // ph4: (mq1,nq1)
    if (more) stageB(kt2, 0);
    SBAR;
    MM(1, 1, bB);
    if (more)
      asm volatile("s_waitcnt vmcnt(8)" ::: "memory");
    else
      asm volatile("s_waitcnt vmcnt(0)" ::: "memory");
    SBAR;
    // ph5: kt1 (mq0,nq0)
    ldA(65536, 0);
    ldB(65536, 0, bA);
    if (more) stageA(kt2, 1);
    SBAR;
    asm volatile("s_waitcnt lgkmcnt(0)" ::: "memory");
    SFENCE;
    MM(0, 0, bA);
    if (more) asm volatile("s_waitcnt vmcnt(6)" ::: "memory");
    SBAR;
    // ph6: (mq0,nq1)
    ldB(65536, 1, bB);
    if (more) stageB(kt2, 1);
    SBAR;
    asm volatile("s_waitcnt lgkmcnt(0)" ::: "memory");
    SFENCE;
    MM(0, 1, bB);
    SBAR;
    // ph7: (mq1,nq0)
    ldA(65536, 1);
    if (more) stageA(kt3, 0);
    SBAR;
    asm volatile("s_waitcnt lgkmcnt(0)" ::: "memory");
    SFENCE;
    MM(1, 0, bA);
    SBAR;
    // ph8: (mq1,nq1)
    if (more) stageB(kt3, 0);
    SBAR;
    MM(1, 1, bB);
    if (more) asm volatile("s_waitcnt vmcnt(8)" ::: "memory");
    SBAR;
  }

  // epilogue: C/D col = lane&15, row = (lane>>4)*4 + reg
#pragma unroll
  for (int mq = 0; mq < 2; ++mq)
#pragma unroll
    for (int mi = 0; mi < 4; ++mi) {
      const int rbase = m0 + mq * 128 + wr * 64 + mi * 16 + (lane >> 4) * 4;
#pragma unroll
      for (int nq = 0; nq < 2; ++nq)
#pragma unroll
        for (int ni = 0; ni < 2; ++ni) {
          const int col = n0 + nq * 128 + wc * 32 + ni * 16 + fr;
          const f32x4 a = acc[mq * 4 + mi][nq * 2 + ni];
          if constexpr (MODE == 0) {
            const float bv = bias[e * ldn + col];
#pragma unroll
            for (int r = 0; r < 4; ++r) {
              float v = a[r] + bv;
              v = v > 0.f ? v : 0.f;
              Hout[(size_t)(rbase + r) * ldn + col] = f2bf(v);
            }
          } else {
            float* Pp = P + bz * pStride;
#pragma unroll
            for (int r = 0; r < 4; ++r)
              Pp[(size_t)(rbase + r) * ODIM + col] = a[r];
          }
        }
    }
}

// ---------------- GEMM1: xg @ wt1 -> h (relu + b1) ----------------
__global__ __launch_bounds__(512, 2) void moe_gemm1(
    const u16* __restrict__ xg, const u16* __restrict__ wt1,
    const float* __restrict__ b1, const int* __restrict__ tile_e,
    const int* __restrict__ tile_m, const int* __restrict__ meta,
    u16* __restrict__ h) {
  __shared__ __align__(16) char lds[131072];
  const int orig = blockIdx.y * MAXT + blockIdx.x;  // nwg = 368 = 8*46
  const int xcd = orig & 7;
  const int idx = orig >> 3;  // 0..45
  const int by = xcd * 2 + idx / MAXT;
  const int bx = idx % MAXT;
  if (bx >= meta[0]) return;
  gemm8p_core<0>(lds, bx, by, 0, xg, DDIM, wt1, DDIM, HDIM, b1, tile_e,
                 tile_m, h, HDIM, nullptr, 0, DDIM / 64, 0);
}

// ---------------- GEMM2: h @ wt2 -> P (z=2 K-split) ----------------
__global__ __launch_bounds__(512, 2) void moe_gemm2(
    const u16* __restrict__ h, const u16* __restrict__ wt2,
    const int* __restrict__ tile_e, const int* __restrict__ tile_m,
    const int* __restrict__ meta, float* __restrict__ P, size_t pStride) {
  __shared__ __align__(16) char lds[131072];
  const int orig = (blockIdx.z * 4 + blockIdx.y) * MAXT + blockIdx.x;  // 184
  const int xcd = orig & 7;
  const int idx = orig >> 3;            // 0..22
  const int wg = xcd * MAXT + idx;      // contiguous per XCD
  const int z = wg / 92;
  const int rem = wg % 92;
  const int by = rem / MAXT;
  const int bx = rem % MAXT;
  if (bx >= meta[0]) return;
  gemm8p_core<1>(lds, bx, by, z, h, HDIM, wt2, HDIM, ODIM, nullptr, tile_e,
                 tile_m, nullptr, 0, P, pStride, 32, z * 2048);
}

// ---------------- reduce: out[tok] = P0 + P1 + b2 ----------------
__global__ __launch_bounds__(256) void reduce_kernel(
    const float* __restrict__ P, size_t pStride, const int* __restrict__ rowmap,
    const int* __restrict__ tile_e, const int* __restrict__ tile_m,
    const int* __restrict__ meta, const float* __restrict__ b2,
    float* __restrict__ out) {
  if ((int)blockIdx.x >= meta[0]) return;
  const int e = tile_e[blockIdx.x];
  const int m0 = tile_m[blockIdx.x];
  const int c0 = blockIdx.y * 128;
#pragma unroll 1
  for (int it = 0; it < 32; ++it) {
    int idx = it * 256 + threadIdx.x;  // 8192 float4 per block (256 rows)
    int r = idx >> 5, cq = idx & 31;
    int row = m0 + r;
    int tok = rowmap[row];
    if (tok < 0) continue;
    int c = c0 + cq * 4;
    float4 a = *(const float4*)(P + (size_t)row * ODIM + c);
    float4 b = *(const float4*)(P + pStride + (size_t)row * ODIM + c);
    float4 bb = *(const float4*)(b2 + (size_t)e * ODIM + c);
    float4 o;
    o.x = a.x + b.x + bb.x;
    o.y = a.y + b.y + bb.y;
    o.z = a.z + b.z + bb.z;
    o.w = a.w + b.w + bb.w;
    *(float4*)(out + (size_t)tok * ODIM + c) = o;
  }
}

extern "C" void kernel_launch(void* const* d_in, const int* in_sizes, int n_in,
                              void* d_out, int out_size, void* d_ws,
                              size_t ws_size, hipStream_t stream) {
  const float* x = (const float*)d_in[0];
  const float* Wg = (const float*)d_in[1];
  const float* bg = (const float*)d_in[2];
  const float* W1 = (const float*)d_in[3];
  const float* b1 = (const float*)d_in[4];
  const float* W2 = (const float*)d_in[5];
  const float* b2 = (const float*)d_in[6];
  const float* wbal = (const float*)d_in[7];
  float* out = (float*)d_out;

  char* ws = (char*)d_ws;
  int* counts = (int*)(ws + 0);
  int* fill = (int*)(ws + 64);
  int* offp = (int*)(ws + 128);
  int* meta = (int*)(ws + 192);
  int* tile_e = (int*)(ws + 256);
  int* tile_m = (int*)(ws + 512);
  int* assign = (int*)(ws + 4096);
  int* rowmap = (int*)(ws + 20480);        // 5888 ints
  u16* xg = (u16*)(ws + 65536);            // 5888x1024 bf16     (12.1 MB)
  u16* h = (u16*)(ws + 12582912);          // 5888x4096 bf16     (48.2 MB)
  float* P = (float*)(ws + 61865984);      // 2x5888x1024 fp32   (48.2 MB)
  u16* wt1 = (u16*)(ws + 110100480);       // [8][4096][1024] bf16 (67.1 MB)
  u16* wt2 = (u16*)(ws + 177209344);       // [8][1024][4096] bf16 (67.1 MB)
  const size_t pStride = (size_t)MROWS * ODIM;

  init_kernel<<<27, 256, 0, stream>>>((int*)ws, rowmap);
  gate_kernel<<<BTOK / 4, 256, 0, stream>>>(x, Wg, bg, assign, counts);
  setup_kernel<<<1, 64, 0, stream>>>(counts, wbal, offp, tile_e, tile_m, meta,
                                     out + (size_t)BTOK * ODIM);
  gather_kernel<<<BTOK, 256, 0, stream>>>(x, assign, offp, fill, rowmap, xg);

  // W1 [1024][4096] -> wt1 [8][4096][1024]
  transpose_conv<<<dim3(DDIM / 256, HDIM / 64, NEXP), 256, 0, stream>>>(
      W1, wt1, HDIM, DDIM);
  // W2 [4096][1024] -> wt2 [8][1024][4096]
  transpose_conv<<<dim3(HDIM / 256, ODIM / 64, NEXP), 256, 0, stream>>>(
      W2, wt2, ODIM, HDIM);

  moe_gemm1<<<dim3(MAXT, HDIM / 256), 512, 0, stream>>>(
      xg, wt1, b1, tile_e, tile_m, meta, h);
  moe_gemm2<<<dim3(MAXT, ODIM / 256, 2), 512, 0, stream>>>(
      h, wt2, tile_e, tile_m, meta, P, pStride);
  reduce_kernel<<<dim3(MAXT, ODIM / 128), 256, 0, stream>>>(
      P, pStride, rowmap, tile_e, tile_m, meta, b2, out);
}

// Round 13
// 352.416 us; speedup vs baseline: 1.0639x; 1.0008x over previous
//
#include <hip/hip_runtime.h>
#include <hip/hip_bf16.h>

typedef unsigned short u16;
typedef __attribute__((ext_vector_type(8))) short bf16x8;
typedef __attribute__((ext_vector_type(4))) float f32x4;

#define BTOK 4096
#define DDIM 1024
#define NEXP 8
#define HDIM 4096
#define ODIM 1024
#define MAXT 23             // max 256-row tiles: 16 + 7
#define MROWS (MAXT * 256)  // 5888

__device__ __forceinline__ u16 f2bf(float f) {
  unsigned u = __float_as_uint(f);
  return (u16)((u + 0x7FFFu + ((u >> 16) & 1u)) >> 16);  // RNE
}
__device__ __forceinline__ u16 cvt_bf(float f) {
  __hip_bfloat16 h = __float2bfloat16(f);
  u16 r;
  __builtin_memcpy(&r, &h, 2);
  return r;
}
__device__ __forceinline__ void gload16(const void* g, void* l) {
  __builtin_amdgcn_global_load_lds(
      (const __attribute__((address_space(1))) void*)g,
      (__attribute__((address_space(3))) void*)l, 16, 0, 0);
}

#define SFENCE __builtin_amdgcn_sched_barrier(0)
#define SBAR                        \
  do {                              \
    SFENCE;                         \
    __builtin_amdgcn_s_barrier();   \
    SFENCE;                         \
  } while (0)

// ---------------- init ----------------
__global__ __launch_bounds__(256) void init_kernel(int* __restrict__ ctrl,
                                                   int* __restrict__ rowmap) {
  int i = blockIdx.x * 256 + threadIdx.x;  // grid 27*256 = 6912
  if (i < 1024)
    ctrl[i] = 0;
  else
    rowmap[i - 1024] = -1;  // 5888 entries
}

// ---------------- gating ----------------
__global__ __launch_bounds__(256) void gate_kernel(
    const float* __restrict__ x, const float* __restrict__ Wg,
    const float* __restrict__ bg, int* __restrict__ assign,
    int* __restrict__ counts) {
  int wave = threadIdx.x >> 6;
  int lane = threadIdx.x & 63;
  int b = blockIdx.x * 4 + wave;
  const float* xr = x + (size_t)b * DDIM;
  double acc[NEXP];
#pragma unroll
  for (int e = 0; e < NEXP; ++e) acc[e] = 0.0;
  for (int d = lane; d < DDIM; d += 64) {
    float xv = xr[d];
    const float4* wrow = (const float4*)(Wg + d * NEXP);
    float4 w0 = wrow[0], w1 = wrow[1];
    acc[0] += (double)xv * (double)w0.x;
    acc[1] += (double)xv * (double)w0.y;
    acc[2] += (double)xv * (double)w0.z;
    acc[3] += (double)xv * (double)w0.w;
    acc[4] += (double)xv * (double)w1.x;
    acc[5] += (double)xv * (double)w1.y;
    acc[6] += (double)xv * (double)w1.z;
    acc[7] += (double)xv * (double)w1.w;
  }
#pragma unroll
  for (int e = 0; e < NEXP; ++e) {
    double v = acc[e];
#pragma unroll
    for (int off = 32; off > 0; off >>= 1) v += __shfl_xor(v, off);
    acc[e] = v;
  }
  if (lane == 0) {
    int best = 0;
    double bv = acc[0] + (double)bg[0];
#pragma unroll
    for (int e = 1; e < NEXP; ++e) {
      double v = acc[e] + (double)bg[e];
      if (v > bv) { bv = v; best = e; }
    }
    assign[b] = best;
    atomicAdd(&counts[best], 1);
  }
}

// ---------------- setup (256-pad) ----------------
__global__ void setup_kernel(const int* __restrict__ counts,
                             const float* __restrict__ wbal,
                             int* __restrict__ offp, int* __restrict__ tile_e,
                             int* __restrict__ tile_m, int* __restrict__ meta,
                             float* __restrict__ loss_out) {
  if (threadIdx.x != 0 || blockIdx.x != 0) return;
  int off = 0, nt = 0;
  for (int e = 0; e < NEXP; ++e) {
    offp[e] = off;
    int pc = (counts[e] + 255) & ~255;
    for (int t = 0; t < (pc >> 8); ++t) {
      tile_e[nt] = e;
      tile_m[nt] = off + t * 256;
      ++nt;
    }
    off += pc;
  }
  offp[NEXP] = off;
  meta[0] = nt;
  float mean = (float)BTOK / (float)NEXP;
  float s = 0.f;
  for (int e = 0; e < NEXP; ++e) {
    float d = (float)counts[e] - mean;
    s += d * d;
  }
  loss_out[0] = s / (float)NEXP * wbal[0];
}

// ---------------- gather ----------------
__global__ __launch_bounds__(256) void gather_kernel(
    const float* __restrict__ x, const int* __restrict__ assign,
    const int* __restrict__ offp, int* __restrict__ fill,
    int* __restrict__ rowmap, u16* __restrict__ xg) {
  int b = blockIdx.x;
  __shared__ int srow;
  if (threadIdx.x == 0) {
    int e = assign[b];
    int pos = atomicAdd(&fill[e], 1);
    int row = offp[e] + pos;
    rowmap[row] = b;
    srow = row;
  }
  __syncthreads();
  int row = srow;
  float4 v = *(const float4*)(x + (size_t)b * DDIM + threadIdx.x * 4);
  ushort4 o;
  o.x = f2bf(v.x);
  o.y = f2bf(v.y);
  o.z = f2bf(v.z);
  o.w = f2bf(v.w);
  *(ushort4*)(xg + (size_t)row * DDIM + threadIdx.x * 4) = o;
}

// ---------------- transpose v3 (round-11): fp32 [K][N] -> bf16 [N][K] --------
__global__ __launch_bounds__(256) void transpose_conv(
    const float* __restrict__ W, u16* __restrict__ wt, int N, int K) {
  const int e = blockIdx.z;
  const int kb = blockIdx.x * 256, nb = blockIdx.y * 64;
  __shared__ __align__(16) float lds[256][66];
  const float* src = W + (size_t)e * K * N;
  const int t = threadIdx.x;
  const int rr = t >> 4, cc = (t & 15) * 4;
#pragma unroll
  for (int p = 0; p < 16; ++p) {
    float4 v =
        *(const float4*)(src + (size_t)(kb + rr + p * 16) * N + nb + cc);
    *(float4*)&lds[rr + p * 16][cc] = v;
  }
  __syncthreads();
  const int n = t & 63, kg = (t >> 6) * 64;
  alignas(16) u16 tmp[64];
#pragma unroll
  for (int i = 0; i < 64; ++i) tmp[i] = cvt_bf(lds[kg + i][n]);
  u16* dst = wt + ((size_t)e * N + nb + n) * K + kb + kg;
#pragma unroll
  for (int q = 0; q < 8; ++q) *(float4*)(dst + q * 8) = *(float4*)&tmp[q * 8];
}

// ---------------- 8-phase 256x256 GEMM core (m201 template port) -------------
// BM=BN=256, BK=64, 8 waves (2M x 4N), wave out = 4 scattered 64x32 patches:
// rows mq*128+wr*64+mi*16, cols nq*128+wc*32+ni*16. 16 MFMA/phase (quadrant).
// LDS 128KB: buf d(64KB) = {A-lo,A-hi,B-lo,B-hi} 16KB regions, rows 128B,
// granule swizzle g = koct ^ (r&7) (b128 frag reads at the 8-cy bank floor;
// gload_lds linear dest + inverse-permuted source keeps 128B coalescing).
// Stage 1 half-tile/phase (2 gloads/thread), 3 half-tiles in flight; counted
// vmcnt ledger: end-ph1/5 vmcnt(6), end-ph4/8 vmcnt(8) (hand-verified, incl.
// prologue + overwrite safety). setprio(1) around MFMA clusters (T5).
template <int MODE>
__device__ __forceinline__ void gemm8p_core(
    char* lds, int bx, int by, int bz, const u16* __restrict__ A, int lda,
    const u16* __restrict__ BT, int ldb, int nbRows,
    const float* __restrict__ bias, const int* __restrict__ tile_e,
    const int* __restrict__ tile_m, u16* __restrict__ Hout, int ldn,
    float* __restrict__ P, size_t pStride, int NT, int kOff) {
  const int e = tile_e[bx];
  const int m0 = tile_m[bx];
  const int n0 = by * 256;

  const int tid = threadIdx.x;  // [0,512)
  const int lane = tid & 63;
  const int wid = tid >> 6;
  const int wr = wid >> 2;  // 0..1
  const int wc = wid & 3;   // 0..3
  const int fr = lane & 15;
  const int kqr = lane >> 4;

  // staging: unit u (r=u>>3, g=u&7) holds source koct = g ^ (r&7)
  const int rS = tid >> 3, gS = tid & 7;
  const int koctOff = (gS ^ (rS & 7)) * 8;  // u16 elems
  const u16* aB0 = A + (size_t)(m0 + rS) * lda + kOff + koctOff;
  const u16* bB0 = BT + ((size_t)e * nbRows + n0 + rS) * ldb + kOff + koctOff;

  auto stageA = [&](int kt, int half) {
    char* dst = lds + (kt & 1) * 65536 + half * 16384 + tid * 16;
    const u16* s = aB0 + (size_t)(half * 128) * lda + kt * 64;
    gload16(s, dst);
    gload16(s + (size_t)64 * lda, dst + 8192);
  };
  auto stageB = [&](int kt, int half) {
    char* dst = lds + (kt & 1) * 65536 + 32768 + half * 16384 + tid * 16;
    const u16* s = bB0 + (size_t)(half * 128) * ldb + kt * 64;
    gload16(s, dst);
    gload16(s + (size_t)64 * ldb, dst + 8192);
  };

  // fragment byte offsets within a 16KB region
  int aOff[4][2], bOff[2][2];
#pragma unroll
  for (int mi = 0; mi < 4; ++mi) {
    int r = wr * 64 + mi * 16 + fr;  // [0,128)
#pragma unroll
    for (int ks = 0; ks < 2; ++ks)
      aOff[mi][ks] = r * 128 + (((ks * 4 + kqr) ^ (r & 7)) * 16);
  }
#pragma unroll
  for (int ni = 0; ni < 2; ++ni) {
    int c = wc * 32 + ni * 16 + fr;  // [0,128)
#pragma unroll
    for (int ks = 0; ks < 2; ++ks)
      bOff[ni][ks] = c * 128 + (((ks * 4 + kqr) ^ (c & 7)) * 16);
  }

  f32x4 acc[8][4];
#pragma unroll
  for (int i = 0; i < 8; ++i)
#pragma unroll
    for (int j = 0; j < 4; ++j)
#pragma unroll
      for (int r = 0; r < 4; ++r) acc[i][j][r] = 0.f;

  bf16x8 af[4][2], bA[2][2], bB[2][2];

  auto ldA = [&](int dB, int mq) {
    const char* rg = lds + dB + mq * 16384;
#pragma unroll
    for (int mi = 0; mi < 4; ++mi)
#pragma unroll
      for (int ks = 0; ks < 2; ++ks)
        af[mi][ks] = *(const bf16x8*)(rg + aOff[mi][ks]);
  };
  auto ldB = [&](int dB, int nq, bf16x8 (&bf)[2][2]) {
    const char* rg = lds + dB + 32768 + nq * 16384;
#pragma unroll
    for (int ni = 0; ni < 2; ++ni)
#pragma unroll
      for (int ks = 0; ks < 2; ++ks)
        bf[ni][ks] = *(const bf16x8*)(rg + bOff[ni][ks]);
  };
  auto MM = [&](int mq, int nq, bf16x8 (&bf)[2][2]) {
    __builtin_amdgcn_s_setprio(1);
#pragma unroll
    for (int ks = 0; ks < 2; ++ks)
#pragma unroll
      for (int mi = 0; mi < 4; ++mi)
#pragma unroll
        for (int ni = 0; ni < 2; ++ni)
          acc[mq * 4 + mi][nq * 2 + ni] = __builtin_amdgcn_mfma_f32_16x16x32_bf16(
              af[mi][ks], bf[ni][ks], acc[mq * 4 + mi][nq * 2 + ni], 0, 0, 0);
    __builtin_amdgcn_s_setprio(0);
  };

  // prologue: A-lo(0),B-lo(0) | A-hi(0),B-hi(0),A-lo(1),B-lo(1)
  stageA(0, 0);
  stageB(0, 0);
  stageA(0, 1);
  stageB(0, 1);
  stageA(1, 0);
  stageB(1, 0);
  asm volatile("s_waitcnt vmcnt(8)" ::: "memory");
  SBAR;

  const int NI = NT >> 1;
#pragma unroll 1
  for (int i = 0; i < NI; ++i) {
    const int kt1 = 2 * i + 1, kt2 = 2 * i + 2, kt3 = 2 * i + 3;
    const bool more = (i + 1 < NI);
    // ph1: kt0 (mq0,nq0)
    ldA(0, 0);
    ldB(0, 0, bA);
    stageA(kt1, 1);
    SBAR;
    asm volatile("s_waitcnt lgkmcnt(0)" ::: "memory");
    SFENCE;
    MM(0, 0, bA);
    asm volatile("s_waitcnt vmcnt(6)" ::: "memory");
    SBAR;
    // ph2: (mq0,nq1)
    ldB(0, 1, bB);
    stageB(kt1, 1);
    SBAR;
    asm volatile("s_waitcnt lgkmcnt(0)" ::: "memory");
    SFENCE;
    MM(0, 1, bB);
    SBAR;
    // ph3: (mq1,nq0)
    ldA(0, 1);
    if (more) stageA(kt2, 0);
    SBAR;
    asm volatile("s_waitcnt lgkmcnt(0)" ::: "memory");
    SFENCE;
    MM(1, 0, bA);
    SBAR;
    // ph4: (mq1,nq1)
    if (more) stageB(kt2, 0);
    SBAR;
    MM(1, 1, bB);
    if (more)
      asm volatile("s_waitcnt vmcnt(8)" ::: "memory");
    else
      asm volatile("s_waitcnt vmcnt(0)" ::: "memory");
    SBAR;
    // ph5: kt1 (mq0,nq0)
    ldA(65536, 0);
    ldB(65536, 0, bA);
    if (more) stageA(kt2, 1);
    SBAR;
    asm volatile("s_waitcnt lgkmcnt(0)" ::: "memory");
    SFENCE;
    MM(0, 0, bA);
    if (more) asm volatile("s_waitcnt vmcnt(6)" ::: "memory");
    SBAR;
    // ph6: (mq0,nq1)
    ldB(65536, 1, bB);
    if (more) stageB(kt2, 1);
    SBAR;
    asm volatile("s_waitcnt lgkmcnt(0)" ::: "memory");
    SFENCE;
    MM(0, 1, bB);
    SBAR;
    // ph7: (mq1,nq0)
    ldA(65536, 1);
    if (more) stageA(kt3, 0);
    SBAR;
    asm volatile("s_waitcnt lgkmcnt(0)" ::: "memory");
    SFENCE;
    MM(1, 0, bA);
    SBAR;
    // ph8: (mq1,nq1)
    if (more) stageB(kt3, 0);
    SBAR;
    MM(1, 1, bB);
    if (more) asm volatile("s_waitcnt vmcnt(8)" ::: "memory");
    SBAR;
  }

  // epilogue: C/D col = lane&15, row = (lane>>4)*4 + reg
#pragma unroll
  for (int mq = 0; mq < 2; ++mq)
#pragma unroll
    for (int mi = 0; mi < 4; ++mi) {
      const int rbase = m0 + mq * 128 + wr * 64 + mi * 16 + (lane >> 4) * 4;
#pragma unroll
      for (int nq = 0; nq < 2; ++nq)
#pragma unroll
        for (int ni = 0; ni < 2; ++ni) {
          const int col = n0 + nq * 128 + wc * 32 + ni * 16 + fr;
          const f32x4 a = acc[mq * 4 + mi][nq * 2 + ni];
          if constexpr (MODE == 0) {
            const float bv = bias[e * ldn + col];
#pragma unroll
            for (int r = 0; r < 4; ++r) {
              float v = a[r] + bv;
              v = v > 0.f ? v : 0.f;
              Hout[(size_t)(rbase + r) * ldn + col] = f2bf(v);
            }
          } else {
            float* Pp = P + bz * pStride;
#pragma unroll
            for (int r = 0; r < 4; ++r)
              Pp[(size_t)(rbase + r) * ODIM + col] = a[r];
          }
        }
    }
}

// ---------------- GEMM1: xg @ wt1 -> h (relu + b1) ----------------
__global__ __launch_bounds__(512, 2) void moe_gemm1(
    const u16* __restrict__ xg, const u16* __restrict__ wt1,
    const float* __restrict__ b1, const int* __restrict__ tile_e,
    const int* __restrict__ tile_m, const int* __restrict__ meta,
    u16* __restrict__ h) {
  __shared__ __align__(16) char lds[131072];
  const int orig = blockIdx.y * MAXT + blockIdx.x;  // nwg = 368 = 8*46
  const int xcd = orig & 7;
  const int idx = orig >> 3;  // 0..45
  const int by = xcd * 2 + idx / MAXT;
  const int bx = idx % MAXT;
  if (bx >= meta[0]) return;
  gemm8p_core<0>(lds, bx, by, 0, xg, DDIM, wt1, DDIM, HDIM, b1, tile_e,
                 tile_m, h, HDIM, nullptr, 0, DDIM / 64, 0);
}

// ---------------- GEMM2: h @ wt2 -> P (z=2 K-split) ----------------
__global__ __launch_bounds__(512, 2) void moe_gemm2(
    const u16* __restrict__ h, const u16* __restrict__ wt2,
    const int* __restrict__ tile_e, const int* __restrict__ tile_m,
    const int* __restrict__ meta, float* __restrict__ P, size_t pStride) {
  __shared__ __align__(16) char lds[131072];
  const int orig = (blockIdx.z * 4 + blockIdx.y) * MAXT + blockIdx.x;  // 184
  const int xcd = orig & 7;
  const int idx = orig >> 3;            // 0..22
  const int wg = xcd * MAXT + idx;      // contiguous per XCD
  const int z = wg / 92;
  const int rem = wg % 92;
  const int by = rem / MAXT;
  const int bx = rem % MAXT;
  if (bx >= meta[0]) return;
  gemm8p_core<1>(lds, bx, by, z, h, HDIM, wt2, HDIM, ODIM, nullptr, tile_e,
                 tile_m, nullptr, 0, P, pStride, 32, z * 2048);
}

// ---------------- reduce: out[tok] = P0 + P1 + b2 ----------------
__global__ __launch_bounds__(256) void reduce_kernel(
    const float* __restrict__ P, size_t pStride, const int* __restrict__ rowmap,
    const int* __restrict__ tile_e, const int* __restrict__ tile_m,
    const int* __restrict__ meta, const float* __restrict__ b2,
    float* __restrict__ out) {
  if ((int)blockIdx.x >= meta[0]) return;
  const int e = tile_e[blockIdx.x];
  const int m0 = tile_m[blockIdx.x];
  const int c0 = blockIdx.y * 128;
#pragma unroll 1
  for (int it = 0; it < 32; ++it) {
    int idx = it * 256 + threadIdx.x;  // 8192 float4 per block (256 rows)
    int r = idx >> 5, cq = idx & 31;
    int row = m0 + r;
    int tok = rowmap[row];
    if (tok < 0) continue;
    int c = c0 + cq * 4;
    float4 a = *(const float4*)(P + (size_t)row * ODIM + c);
    float4 b = *(const float4*)(P + pStride + (size_t)row * ODIM + c);
    float4 bb = *(const float4*)(b2 + (size_t)e * ODIM + c);
    float4 o;
    o.x = a.x + b.x + bb.x;
    o.y = a.y + b.y + bb.y;
    o.z = a.z + b.z + bb.z;
    o.w = a.w + b.w + bb.w;
    *(float4*)(out + (size_t)tok * ODIM + c) = o;
  }
}

extern "C" void kernel_launch(void* const* d_in, const int* in_sizes, int n_in,
                              void* d_out, int out_size, void* d_ws,
                              size_t ws_size, hipStream_t stream) {
  const float* x = (const float*)d_in[0];
  const float* Wg = (const float*)d_in[1];
  const float* bg = (const float*)d_in[2];
  const float* W1 = (const float*)d_in[3];
  const float* b1 = (const float*)d_in[4];
  const float* W2 = (const float*)d_in[5];
  const float* b2 = (const float*)d_in[6];
  const float* wbal = (const float*)d_in[7];
  float* out = (float*)d_out;

  char* ws = (char*)d_ws;
  int* counts = (int*)(ws + 0);
  int* fill = (int*)(ws + 64);
  int* offp = (int*)(ws + 128);
  int* meta = (int*)(ws + 192);
  int* tile_e = (int*)(ws + 256);
  int* tile_m = (int*)(ws + 512);
  int* assign = (int*)(ws + 4096);
  int* rowmap = (int*)(ws + 20480);        // 5888 ints
  u16* xg = (u16*)(ws + 65536);            // 5888x1024 bf16     (12.1 MB)
  u16* h = (u16*)(ws + 12582912);          // 5888x4096 bf16     (48.2 MB)
  float* P = (float*)(ws + 61865984);      // 2x5888x1024 fp32   (48.2 MB)
  u16* wt1 = (u16*)(ws + 110100480);       // [8][4096][1024] bf16 (67.1 MB)
  u16* wt2 = (u16*)(ws + 177209344);       // [8][1024][4096] bf16 (67.1 MB)
  const size_t pStride = (size_t)MROWS * ODIM;

  init_kernel<<<27, 256, 0, stream>>>((int*)ws, rowmap);
  gate_kernel<<<BTOK / 4, 256, 0, stream>>>(x, Wg, bg, assign, counts);
  setup_kernel<<<1, 64, 0, stream>>>(counts, wbal, offp, tile_e, tile_m, meta,
                                     out + (size_t)BTOK * ODIM);
  gather_kernel<<<BTOK, 256, 0, stream>>>(x, assign, offp, fill, rowmap, xg);

  // W1 [1024][4096] -> wt1 [8][4096][1024]
  transpose_conv<<<dim3(DDIM / 256, HDIM / 64, NEXP), 256, 0, stream>>>(
      W1, wt1, HDIM, DDIM);
  // W2 [4096][1024] -> wt2 [8][1024][4096]
  transpose_conv<<<dim3(HDIM / 256, ODIM / 64, NEXP), 256, 0, stream>>>(
      W2, wt2, ODIM, HDIM);

  moe_gemm1<<<dim3(MAXT, HDIM / 256), 512, 0, stream>>>(
      xg, wt1, b1, tile_e, tile_m, meta, h);
  moe_gemm2<<<dim3(MAXT, ODIM / 256, 2), 512, 0, stream>>>(
      h, wt2, tile_e, tile_m, meta, P, pStride);
  reduce_kernel<<<dim3(MAXT, ODIM / 128), 256, 0, stream>>>(
      P, pStride, rowmap, tile_e, tile_m, meta, b2, out);
}

// Round 14
// 352.370 us; speedup vs baseline: 1.0641x; 1.0001x over previous
//
#include <hip/hip_runtime.h>
#include <hip/hip_bf16.h>

typedef unsigned short u16;
typedef __attribute__((ext_vector_type(8))) short bf16x8;
typedef __attribute__((ext_vector_type(4))) float f32x4;

#define BTOK 4096
#define DDIM 1024
#define NEXP 8
#define HDIM 4096
#define ODIM 1024
#define MAXT 23             // max 256-row tiles: 16 + 7
#define MROWS (MAXT * 256)  // 5888

__device__ __forceinline__ u16 f2bf(float f) {
  unsigned u = __float_as_uint(f);
  return (u16)((u + 0x7FFFu + ((u >> 16) & 1u)) >> 16);  // RNE
}
__device__ __forceinline__ u16 cvt_bf(float f) {
  __hip_bfloat16 h = __float2bfloat16(f);
  u16 r;
  __builtin_memcpy(&r, &h, 2);
  return r;
}
__device__ __forceinline__ void gload16(const void* g, void* l) {
  __builtin_amdgcn_global_load_lds(
      (const __attribute__((address_space(1))) void*)g,
      (__attribute__((address_space(3))) void*)l, 16, 0, 0);
}

#define SFENCE __builtin_amdgcn_sched_barrier(0)
#define SBAR                        \
  do {                              \
    SFENCE;                         \
    __builtin_amdgcn_s_barrier();   \
    SFENCE;                         \
  } while (0)

// ---------------- init ----------------
__global__ __launch_bounds__(256) void init_kernel(int* __restrict__ ctrl,
                                                   int* __restrict__ rowmap) {
  int i = blockIdx.x * 256 + threadIdx.x;  // grid 27*256 = 6912
  if (i < 1024)
    ctrl[i] = 0;
  else
    rowmap[i - 1024] = -1;  // 5888 entries
}

// ---------------- gating ----------------
__global__ __launch_bounds__(256) void gate_kernel(
    const float* __restrict__ x, const float* __restrict__ Wg,
    const float* __restrict__ bg, int* __restrict__ assign,
    int* __restrict__ counts) {
  int wave = threadIdx.x >> 6;
  int lane = threadIdx.x & 63;
  int b = blockIdx.x * 4 + wave;
  const float* xr = x + (size_t)b * DDIM;
  double acc[NEXP];
#pragma unroll
  for (int e = 0; e < NEXP; ++e) acc[e] = 0.0;
  for (int d = lane; d < DDIM; d += 64) {
    float xv = xr[d];
    const float4* wrow = (const float4*)(Wg + d * NEXP);
    float4 w0 = wrow[0], w1 = wrow[1];
    acc[0] += (double)xv * (double)w0.x;
    acc[1] += (double)xv * (double)w0.y;
    acc[2] += (double)xv * (double)w0.z;
    acc[3] += (double)xv * (double)w0.w;
    acc[4] += (double)xv * (double)w1.x;
    acc[5] += (double)xv * (double)w1.y;
    acc[6] += (double)xv * (double)w1.z;
    acc[7] += (double)xv * (double)w1.w;
  }
#pragma unroll
  for (int e = 0; e < NEXP; ++e) {
    double v = acc[e];
#pragma unroll
    for (int off = 32; off > 0; off >>= 1) v += __shfl_xor(v, off);
    acc[e] = v;
  }
  if (lane == 0) {
    int best = 0;
    double bv = acc[0] + (double)bg[0];
#pragma unroll
    for (int e = 1; e < NEXP; ++e) {
      double v = acc[e] + (double)bg[e];
      if (v > bv) { bv = v; best = e; }
    }
    assign[b] = best;
    atomicAdd(&counts[best], 1);
  }
}

// ---------------- setup (256-pad) ----------------
__global__ void setup_kernel(const int* __restrict__ counts,
                             const float* __restrict__ wbal,
                             int* __restrict__ offp, int* __restrict__ tile_e,
                             int* __restrict__ tile_m, int* __restrict__ meta,
                             float* __restrict__ loss_out) {
  if (threadIdx.x != 0 || blockIdx.x != 0) return;
  int off = 0, nt = 0;
  for (int e = 0; e < NEXP; ++e) {
    offp[e] = off;
    int pc = (counts[e] + 255) & ~255;
    for (int t = 0; t < (pc >> 8); ++t) {
      tile_e[nt] = e;
      tile_m[nt] = off + t * 256;
      ++nt;
    }
    off += pc;
  }
  offp[NEXP] = off;
  meta[0] = nt;
  float mean = (float)BTOK / (float)NEXP;
  float s = 0.f;
  for (int e = 0; e < NEXP; ++e) {
    float d = (float)counts[e] - mean;
    s += d * d;
  }
  loss_out[0] = s / (float)NEXP * wbal[0];
}

// ---------------- gather ----------------
__global__ __launch_bounds__(256) void gather_kernel(
    const float* __restrict__ x, const int* __restrict__ assign,
    const int* __restrict__ offp, int* __restrict__ fill,
    int* __restrict__ rowmap, u16* __restrict__ xg) {
  int b = blockIdx.x;
  __shared__ int srow;
  if (threadIdx.x == 0) {
    int e = assign[b];
    int pos = atomicAdd(&fill[e], 1);
    int row = offp[e] + pos;
    rowmap[row] = b;
    srow = row;
  }
  __syncthreads();
  int row = srow;
  float4 v = *(const float4*)(x + (size_t)b * DDIM + threadIdx.x * 4);
  ushort4 o;
  o.x = f2bf(v.x);
  o.y = f2bf(v.y);
  o.z = f2bf(v.z);
  o.w = f2bf(v.w);
  *(ushort4*)(xg + (size_t)row * DDIM + threadIdx.x * 4) = o;
}

// ---------------- transpose v3 (round-11): fp32 [K][N] -> bf16 [N][K] --------
__global__ __launch_bounds__(256) void transpose_conv(
    const float* __restrict__ W, u16* __restrict__ wt, int N, int K) {
  const int e = blockIdx.z;
  const int kb = blockIdx.x * 256, nb = blockIdx.y * 64;
  __shared__ __align__(16) float lds[256][66];
  const float* src = W + (size_t)e * K * N;
  const int t = threadIdx.x;
  const int rr = t >> 4, cc = (t & 15) * 4;
#pragma unroll
  for (int p = 0; p < 16; ++p) {
    float4 v =
        *(const float4*)(src + (size_t)(kb + rr + p * 16) * N + nb + cc);
    *(float4*)&lds[rr + p * 16][cc] = v;
  }
  __syncthreads();
  const int n = t & 63, kg = (t >> 6) * 64;
  alignas(16) u16 tmp[64];
#pragma unroll
  for (int i = 0; i < 64; ++i) tmp[i] = cvt_bf(lds[kg + i][n]);
  u16* dst = wt + ((size_t)e * N + nb + n) * K + kb + kg;
#pragma unroll
  for (int q = 0; q < 8; ++q) *(float4*)(dst + q * 8) = *(float4*)&tmp[q * 8];
}

// ---------------- 8-phase 256x256 GEMM core (m201 template port) -------------
// BM=BN=256, BK=64, 8 waves (2M x 4N), wave out = 4 scattered 64x32 patches:
// rows mq*128+wr*64+mi*16, cols nq*128+wc*32+ni*16. 16 MFMA/phase (quadrant).
// LDS 128KB: buf d(64KB) = {A-lo,A-hi,B-lo,B-hi} 16KB regions, rows 128B,
// granule swizzle g = koct ^ (r&7) (b128 frag reads at the 8-cy bank floor;
// gload_lds linear dest + inverse-permuted source keeps 128B coalescing).
// Stage 1 half-tile/phase (2 gloads/thread), 3 half-tiles in flight; counted
// vmcnt ledger: end-ph1/5 vmcnt(6), end-ph4/8 vmcnt(8) (hand-verified, incl.
// prologue + overwrite safety). setprio(1) around MFMA clusters (T5).
template <int MODE>
__device__ __forceinline__ void gemm8p_core(
    char* lds, int bx, int by, int bz, const u16* __restrict__ A, int lda,
    const u16* __restrict__ BT, int ldb, int nbRows,
    const float* __restrict__ bias, const int* __restrict__ tile_e,
    const int* __restrict__ tile_m, u16* __restrict__ Hout, int ldn,
    float* __restrict__ P, size_t pStride, int NT, int kOff) {
  const int e = tile_e[bx];
  const int m0 = tile_m[bx];
  const int n0 = by * 256;

  const int tid = threadIdx.x;  // [0,512)
  const int lane = tid & 63;
  const int wid = tid >> 6;
  const int wr = wid >> 2;  // 0..1
  const int wc = wid & 3;   // 0..3
  const int fr = lane & 15;
  const int kqr = lane >> 4;

  // staging: unit u (r=u>>3, g=u&7) holds source koct = g ^ (r&7)
  const int rS = tid >> 3, gS = tid & 7;
  const int koctOff = (gS ^ (rS & 7)) * 8;  // u16 elems
  const u16* aB0 = A + (size_t)(m0 + rS) * lda + kOff + koctOff;
  const u16* bB0 = BT + ((size_t)e * nbRows + n0 + rS) * ldb + kOff + koctOff;

  auto stageA = [&](int kt, int half) {
    char* dst = lds + (kt & 1) * 65536 + half * 16384 + tid * 16;
    const u16* s = aB0 + (size_t)(half * 128) * lda + kt * 64;
    gload16(s, dst);
    gload16(s + (size_t)64 * lda, dst + 8192);
  };
  auto stageB = [&](int kt, int half) {
    char* dst = lds + (kt & 1) * 65536 + 32768 + half * 16384 + tid * 16;
    const u16* s = bB0 + (size_t)(half * 128) * ldb + kt * 64;
    gload16(s, dst);
    gload16(s + (size_t)64 * ldb, dst + 8192);
  };

  // fragment byte offsets within a 16KB region
  int aOff[4][2], bOff[2][2];
#pragma unroll
  for (int mi = 0; mi < 4; ++mi) {
    int r = wr * 64 + mi * 16 + fr;  // [0,128)
#pragma unroll
    for (int ks = 0; ks < 2; ++ks)
      aOff[mi][ks] = r * 128 + (((ks * 4 + kqr) ^ (r & 7)) * 16);
  }
#pragma unroll
  for (int ni = 0; ni < 2; ++ni) {
    int c = wc * 32 + ni * 16 + fr;  // [0,128)
#pragma unroll
    for (int ks = 0; ks < 2; ++ks)
      bOff[ni][ks] = c * 128 + (((ks * 4 + kqr) ^ (c & 7)) * 16);
  }

  f32x4 acc[8][4];
#pragma unroll
  for (int i = 0; i < 8; ++i)
#pragma unroll
    for (int j = 0; j < 4; ++j)
#pragma unroll
      for (int r = 0; r < 4; ++r) acc[i][j][r] = 0.f;

  bf16x8 af[4][2], bA[2][2], bB[2][2];

  auto ldA = [&](int dB, int mq) {
    const char* rg = lds + dB + mq * 16384;
#pragma unroll
    for (int mi = 0; mi < 4; ++mi)
#pragma unroll
      for (int ks = 0; ks < 2; ++ks)
        af[mi][ks] = *(const bf16x8*)(rg + aOff[mi][ks]);
  };
  auto ldB = [&](int dB, int nq, bf16x8 (&bf)[2][2]) {
    const char* rg = lds + dB + 32768 + nq * 16384;
#pragma unroll
    for (int ni = 0; ni < 2; ++ni)
#pragma unroll
      for (int ks = 0; ks < 2; ++ks)
        bf[ni][ks] = *(const bf16x8*)(rg + bOff[ni][ks]);
  };
  auto MM = [&](int mq, int nq, bf16x8 (&bf)[2][2]) {
    __builtin_amdgcn_s_setprio(1);
#pragma unroll
    for (int ks = 0; ks < 2; ++ks)
#pragma unroll
      for (int mi = 0; mi < 4; ++mi)
#pragma unroll
        for (int ni = 0; ni < 2; ++ni)
          acc[mq * 4 + mi][nq * 2 + ni] = __builtin_amdgcn_mfma_f32_16x16x32_bf16(
              af[mi][ks], bf[ni][ks], acc[mq * 4 + mi][nq * 2 + ni], 0, 0, 0);
    __builtin_amdgcn_s_setprio(0);
  };

  // prologue: A-lo(0),B-lo(0) | A-hi(0),B-hi(0),A-lo(1),B-lo(1)
  stageA(0, 0);
  stageB(0, 0);
  stageA(0, 1);
  stageB(0, 1);
  stageA(1, 0);
  stageB(1, 0);
  asm volatile("s_waitcnt vmcnt(8)" ::: "memory");
  SBAR;

  const int NI = NT >> 1;
#pragma unroll 1
  for (int i = 0; i < NI; ++i) {
    const int kt1 = 2 * i + 1, kt2 = 2 * i + 2, kt3 = 2 * i + 3;
    const bool more = (i + 1 < NI);
    // ph1: kt0 (mq0,nq0)
    ldA(0, 0);
    ldB(0, 0, bA);
    stageA(kt1, 1);
    SBAR;
    asm volatile("s_waitcnt lgkmcnt(0)" ::: "memory");
    SFENCE;
    MM(0, 0, bA);
    asm volatile("s_waitcnt vmcnt(6)" ::: "memory");
    SBAR;
    // ph2: (mq0,nq1)
    ldB(0, 1, bB);
    stageB(kt1, 1);
    SBAR;
    asm volatile("s_waitcnt lgkmcnt(0)" ::: "memory");
    SFENCE;
    MM(0, 1, bB);
    SBAR;
    // ph3: (mq1,nq0)
    ldA(0, 1);
    if (more) stageA(kt2, 0);
    SBAR;
    asm volatile("s_waitcnt lgkmcnt(0)" ::: "memory");
    SFENCE;
    MM(1, 0, bA);
    SBAR;
    // ph4: (mq1,nq1)
    if (more) stageB(kt2, 0);
    SBAR;
    MM(1, 1, bB);
    if (more)
      asm volatile("s_waitcnt vmcnt(8)" ::: "memory");
    else
      asm volatile("s_waitcnt vmcnt(0)" ::: "memory");
    SBAR;
    // ph5: kt1 (mq0,nq0)
    ldA(65536, 0);
    ldB(65536, 0, bA);
    if (more) stageA(kt2, 1);
    SBAR;
    asm volatile("s_waitcnt lgkmcnt(0)" ::: "memory");
    SFENCE;
    MM(0, 0, bA);
    if (more) asm volatile("s_waitcnt vmcnt(6)" ::: "memory");
    SBAR;
    // ph6: (mq0,nq1)
    ldB(65536, 1, bB);
    if (more) stageB(kt2, 1);
    SBAR;
    asm volatile("s_waitcnt lgkmcnt(0)" ::: "memory");
    SFENCE;
    MM(0, 1, bB);
    SBAR;
    // ph7: (mq1,nq0)
    ldA(65536, 1);
    if (more) stageA(kt3, 0);
    SBAR;
    asm volatile("s_waitcnt lgkmcnt(0)" ::: "memory");
    SFENCE;
    MM(1, 0, bA);
    SBAR;
    // ph8: (mq1,nq1)
    if (more) stageB(kt3, 0);
    SBAR;
    MM(1, 1, bB);
    if (more) asm volatile("s_waitcnt vmcnt(8)" ::: "memory");
    SBAR;
  }

  // epilogue: C/D col = lane&15, row = (lane>>4)*4 + reg
#pragma unroll
  for (int mq = 0; mq < 2; ++mq)
#pragma unroll
    for (int mi = 0; mi < 4; ++mi) {
      const int rbase = m0 + mq * 128 + wr * 64 + mi * 16 + (lane >> 4) * 4;
#pragma unroll
      for (int nq = 0; nq < 2; ++nq)
#pragma unroll
        for (int ni = 0; ni < 2; ++ni) {
          const int col = n0 + nq * 128 + wc * 32 + ni * 16 + fr;
          const f32x4 a = acc[mq * 4 + mi][nq * 2 + ni];
          if constexpr (MODE == 0) {
            const float bv = bias[e * ldn + col];
#pragma unroll
            for (int r = 0; r < 4; ++r) {
              float v = a[r] + bv;
              v = v > 0.f ? v : 0.f;
              Hout[(size_t)(rbase + r) * ldn + col] = f2bf(v);
            }
          } else {
            float* Pp = P + bz * pStride;
#pragma unroll
            for (int r = 0; r < 4; ++r)
              Pp[(size_t)(rbase + r) * ODIM + col] = a[r];
          }
        }
    }
}

// ---------------- GEMM1: xg @ wt1 -> h (relu + b1) ----------------
__global__ __launch_bounds__(512, 2) void moe_gemm1(
    const u16* __restrict__ xg, const u16* __restrict__ wt1,
    const float* __restrict__ b1, const int* __restrict__ tile_e,
    const int* __restrict__ tile_m, const int* __restrict__ meta,
    u16* __restrict__ h) {
  __shared__ __align__(16) char lds[131072];
  const int orig = blockIdx.y * MAXT + blockIdx.x;  // nwg = 368 = 8*46
  const int xcd = orig & 7;
  const int idx = orig >> 3;  // 0..45
  const int by = xcd * 2 + idx / MAXT;
  const int bx = idx % MAXT;
  if (bx >= meta[0]) return;
  gemm8p_core<0>(lds, bx, by, 0, xg, DDIM, wt1, DDIM, HDIM, b1, tile_e,
                 tile_m, h, HDIM, nullptr, 0, DDIM / 64, 0);
}

// ---------------- GEMM2: h @ wt2 -> P (z=2 K-split) ----------------
__global__ __launch_bounds__(512, 2) void moe_gemm2(
    const u16* __restrict__ h, const u16* __restrict__ wt2,
    const int* __restrict__ tile_e, const int* __restrict__ tile_m,
    const int* __restrict__ meta, float* __restrict__ P, size_t pStride) {
  __shared__ __align__(16) char lds[131072];
  const int orig = (blockIdx.z * 4 + blockIdx.y) * MAXT + blockIdx.x;  // 184
  const int xcd = orig & 7;
  const int idx = orig >> 3;            // 0..22
  const int wg = xcd * MAXT + idx;      // contiguous per XCD
  const int z = wg / 92;
  const int rem = wg % 92;
  const int by = rem / MAXT;
  const int bx = rem % MAXT;
  if (bx >= meta[0]) return;
  gemm8p_core<1>(lds, bx, by, z, h, HDIM, wt2, HDIM, ODIM, nullptr, tile_e,
                 tile_m, nullptr, 0, P, pStride, 32, z * 2048);
}

// ---------------- reduce: out[tok] = P0 + P1 + b2 ----------------
__global__ __launch_bounds__(256) void reduce_kernel(
    const float* __restrict__ P, size_t pStride, const int* __restrict__ rowmap,
    const int* __restrict__ tile_e, const int* __restrict__ tile_m,
    const int* __restrict__ meta, const float* __restrict__ b2,
    float* __restrict__ out) {
  if ((int)blockIdx.x >= meta[0]) return;
  const int e = tile_e[blockIdx.x];
  const int m0 = tile_m[blockIdx.x];
  const int c0 = blockIdx.y * 128;
#pragma unroll 1
  for (int it = 0; it < 32; ++it) {
    int idx = it * 256 + threadIdx.x;  // 8192 float4 per block (256 rows)
    int r = idx >> 5, cq = idx & 31;
    int row = m0 + r;
    int tok = rowmap[row];
    if (tok < 0) continue;
    int c = c0 + cq * 4;
    float4 a = *(const float4*)(P + (size_t)row * ODIM + c);
    float4 b = *(const float4*)(P + pStride + (size_t)row * ODIM + c);
    float4 bb = *(const float4*)(b2 + (size_t)e * ODIM + c);
    float4 o;
    o.x = a.x + b.x + bb.x;
    o.y = a.y + b.y + bb.y;
    o.z = a.z + b.z + bb.z;
    o.w = a.w + b.w + bb.w;
    *(float4*)(out + (size_t)tok * ODIM + c) = o;
  }
}

extern "C" void kernel_launch(void* const* d_in, const int* in_sizes, int n_in,
                              void* d_out, int out_size, void* d_ws,
                              size_t ws_size, hipStream_t stream) {
  const float* x = (const float*)d_in[0];
  const float* Wg = (const float*)d_in[1];
  const float* bg = (const float*)d_in[2];
  const float* W1 = (const float*)d_in[3];
  const float* b1 = (const float*)d_in[4];
  const float* W2 = (const float*)d_in[5];
  const float* b2 = (const float*)d_in[6];
  const float* wbal = (const float*)d_in[7];
  float* out = (float*)d_out;

  char* ws = (char*)d_ws;
  int* counts = (int*)(ws + 0);
  int* fill = (int*)(ws + 64);
  int* offp = (int*)(ws + 128);
  int* meta = (int*)(ws + 192);
  int* tile_e = (int*)(ws + 256);
  int* tile_m = (int*)(ws + 512);
  int* assign = (int*)(ws + 4096);
  int* rowmap = (int*)(ws + 20480);        // 5888 ints
  u16* xg = (u16*)(ws + 65536);            // 5888x1024 bf16     (12.1 MB)
  u16* h = (u16*)(ws + 12582912);          // 5888x4096 bf16     (48.2 MB)
  float* P = (float*)(ws + 61865984);      // 2x5888x1024 fp32   (48.2 MB)
  u16* wt1 = (u16*)(ws + 110100480);       // [8][4096][1024] bf16 (67.1 MB)
  u16* wt2 = (u16*)(ws + 177209344);       // [8][1024][4096] bf16 (67.1 MB)
  const size_t pStride = (size_t)MROWS * ODIM;

  init_kernel<<<27, 256, 0, stream>>>((int*)ws, rowmap);
  gate_kernel<<<BTOK / 4, 256, 0, stream>>>(x, Wg, bg, assign, counts);
  setup_kernel<<<1, 64, 0, stream>>>(counts, wbal, offp, tile_e, tile_m, meta,
                                     out + (size_t)BTOK * ODIM);
  gather_kernel<<<BTOK, 256, 0, stream>>>(x, assign, offp, fill, rowmap, xg);

  // W1 [1024][4096] -> wt1 [8][4096][1024]
  transpose_conv<<<dim3(DDIM / 256, HDIM / 64, NEXP), 256, 0, stream>>>(
      W1, wt1, HDIM, DDIM);
  // W2 [4096][1024] -> wt2 [8][1024][4096]
  transpose_conv<<<dim3(HDIM / 256, ODIM / 64, NEXP), 256, 0, stream>>>(
      W2, wt2, ODIM, HDIM);

  moe_gemm1<<<dim3(MAXT, HDIM / 256), 512, 0, stream>>>(
      xg, wt1, b1, tile_e, tile_m, meta, h);
  moe_gemm2<<<dim3(MAXT, ODIM / 256, 2), 512, 0, stream>>>(
      h, wt2, tile_e, tile_m, meta, P, pStride);
  reduce_kernel<<<dim3(MAXT, ODIM / 128), 256, 0, stream>>>(
      P, pStride, rowmap, tile_e, tile_m, meta, b2, out);
}